// Round 8
// baseline (264.552 us; speedup 1.0000x reference)
//
#include <hip/hip_runtime.h>

// CapsuleLayer fused pipeline, round 15.
//  - R14 POST-MORTEM: REGRESSED (route 98.5->108.5, absmax 0.125). The
//    128-thread 4x4 tiling halved active waves -> phases are per-wave-issue
//    limited, not LDS-pipe saturated; no-max softmax shifted rounding.
//    Route REVERTED to R13 (98.5us, absmax 0.03125).
//  - Evidence recap: R12 (-ih staging) = -7us, R13 (-260 LDS instr in attn)
//    = -1us -> ih ~10-15us, attn not LDS-bound. Remaining budget is
//    inter-kernel: ih re-stages each b's x 4x (64MB) + 16MB ssq round-trip
//    + a launch gap.
//  - R15: FUSE k_ih into k_attn (k_attn2, one block per b): stage x->bf16
//    once, per-wave MFMA ssq (8 n's/wave, bit-identical sequence), ssq in
//    LDS only, FM partial folded into a register before the attn body,
//    attn body verbatim R13. xB/cF2/ssqS alias pS/bufA/tS regions with
//    barrier separation (audited). 3 launches, -64MB traffic.
//  - k_prep2 / k_route3 unchanged (known-good R13).
//  - NO cooperative launches (R6 lesson: harness graph capture fails).

#define EPS_SQ 1e-7f

typedef __attribute__((ext_vector_type(8))) short bf16x8;
typedef __attribute__((ext_vector_type(4))) float floatx4;

__device__ __forceinline__ int lidx(int r, int c) {
  // 64-col fp32 tile, row stride 68 dwords, quad-swizzle (legacy kernels)
  return r * 68 + ((((c >> 2) ^ (r >> 2)) & 15) << 2) + (c & 3);
}
__device__ __forceinline__ int lidx64(int r, int c) {
  // unpadded 64-col fp32 tile, XOR swizzle at float4 granularity.
  // R10: include r>>2 so rows stepping by 4 rotate bank-quads.
  return r * 64 + ((((c >> 2) ^ r ^ (r >> 2)) & 15) << 2) + (c & 3);
}
__device__ __forceinline__ unsigned short f2bf(float f) {
  unsigned u = __float_as_uint(f);
  u += 0x7FFFu + ((u >> 16) & 1u);   // RNE
  return (unsigned short)(u >> 16);
}

// ---------------------------------------------------------------------------
// k_prep2: bid<32: Q_n = M_n.M_n^T ; bid 32..39: A_h = Wq_h.Wk_h^T ;
//          bid 40: symmetric pair matrix K from kmf ;
//          bid 41..72: Wbf = W in bf16 MFMA-B-fragment layout.
// ---------------------------------------------------------------------------
__global__ __launch_bounds__(256) void k_prep2(
    const float* __restrict__ W, const float* __restrict__ Wq,
    const float* __restrict__ Wk, const float* __restrict__ kmf,
    float* __restrict__ Qb, float* __restrict__ Ab, float* __restrict__ Kb,
    unsigned short* __restrict__ Wbf)
{
  const int t = threadIdx.x;
  if (blockIdx.x < 32) {
    __shared__ __align__(16) float Mn[64 * 68];
    const int n = blockIdx.x;
#pragma unroll
    for (int k = 0; k < 4; k++) {
      int lin = t + 256 * k; int d = lin >> 4; int c0 = (lin & 15) << 2;
      *(float4*)&Mn[lidx(d, c0)] = *(const float4*)(W + d * 2048 + n * 64 + c0);
    }
    __syncthreads();
    const int d1 = (t >> 4) * 4, d2 = (t & 15) * 4;
    float acc[4][4] = {};
    for (int cq = 0; cq < 64; cq += 4) {
      float m1[4][4], m2[4][4];
#pragma unroll
      for (int i = 0; i < 4; i++) *(float4*)m1[i] = *(const float4*)&Mn[lidx(d1 + i, cq)];
#pragma unroll
      for (int j = 0; j < 4; j++) *(float4*)m2[j] = *(const float4*)&Mn[lidx(d2 + j, cq)];
#pragma unroll
      for (int i = 0; i < 4; i++)
#pragma unroll
        for (int j = 0; j < 4; j++) {
          float s = 0.f;
#pragma unroll
          for (int k = 0; k < 4; k++) s += m1[i][k] * m2[j][k];
          acc[i][j] += s;
        }
    }
#pragma unroll
    for (int i = 0; i < 4; i++)
      *(float4*)(Qb + n * 4096 + (d1 + i) * 64 + d2) = *(float4*)acc[i];
  } else if (blockIdx.x < 40) {
    __shared__ __align__(16) float wkS[64 * 68];
    __shared__ __align__(16) float wqS[16 * 68];
    const int hb = blockIdx.x - 32;
    const int h = hb & 1, rg = hb >> 1;
#pragma unroll
    for (int k = 0; k < 4; k++) {
      int lin = t + 256 * k; int dp = lin >> 4; int e0 = (lin & 15) << 2;
      *(float4*)&wkS[lidx(dp, e0)] = *(const float4*)(Wk + dp * 128 + h * 64 + e0);
    }
    {
      int dl = t >> 4, e0 = (t & 15) << 2;
      *(float4*)&wqS[lidx(dl, e0)] = *(const float4*)(Wq + (rg * 16 + dl) * 128 + h * 64 + e0);
    }
    __syncthreads();
    const int dl = t >> 4, dp0 = (t & 15) << 2;
    float acc[4] = {};
    for (int e = 0; e < 64; e += 4) {
      float q4[4];
      *(float4*)q4 = *(const float4*)&wqS[lidx(dl, e)];
#pragma unroll
      for (int c = 0; c < 4; c++) {
        float mr[4];
        *(float4*)mr = *(const float4*)&wkS[lidx(dp0 + c, e)];
        acc[c] += q4[0] * mr[0] + q4[1] * mr[1] + q4[2] * mr[2] + q4[3] * mr[3];
      }
    }
    *(float4*)(Ab + h * 4096 + (rg * 16 + dl) * 64 + dp0) = *(float4*)acc;
  } else if (blockIdx.x == 40) {
    __shared__ float Ks[1024];
    *(float4*)&Ks[t * 4] = make_float4(0.f, 0.f, 0.f, 0.f);
    __syncthreads();
    if (t < 248) {
#pragma unroll
      for (int j = 0; j < 2; j++) {
        int p = t * 2 + j;
        if (p < 496) {
          int l = 0, rem = p;
          while (rem >= 31 - l) { rem -= 31 - l; ++l; }
          int r = l + 1 + rem;
          float v = kmf[p];
          Ks[l * 32 + r] = v;
          Ks[r * 32 + l] = v;
        }
      }
    }
    __syncthreads();
    *(float4*)&Kb[t * 4] = *(const float4*)&Ks[t * 4];
  } else {
    // Wbf: per n, element (c,d) at Wbf[n*4096 + c*64 + ((dg^(c&7))<<3) + dl],
    // dg=d>>3, dl=d&7 -- the exact wB layout the old k_ih built per-block.
    const int n = blockIdx.x - 41;
#pragma unroll
    for (int k = 0; k < 2; k++) {
      int lin = t + 256 * k;          // 0..511 = 64 c x 8 dg
      int c = lin >> 3, dg = lin & 7;
      unsigned short tmp[8];
#pragma unroll
      for (int dl = 0; dl < 8; dl++)
        tmp[dl] = f2bf(W[(dg * 8 + dl) * 2048 + n * 64 + c]);
      *(uint4*)&Wbf[n * 4096 + c * 64 + ((dg ^ (c & 7)) << 3)] = *(uint4*)tmp;
    }
  }
}

// ---------------------------------------------------------------------------
// k_route3: routing for TWO b's per 512-thread block. (R13 verbatim)
// ---------------------------------------------------------------------------
__global__ __launch_bounds__(512, 4) void k_route3(
    const float* __restrict__ x, const float* __restrict__ W,
    const float* __restrict__ rinit, const float* __restrict__ Qb,
    float* __restrict__ rs, float* __restrict__ fwv)
{
  __shared__ __align__(16) float smem[2 * 10240];   // 81920 B exactly

  const int t = threadIdx.x;
  const int tb = t >> 8, tt = t & 255;
  const int b = blockIdx.x * 2 + tb;

  float* xs  = smem + tb * 10240;          // 64x64 (swizzled)
  float* bS  = smem + tb * 10240 + 4096;   // 32x64 logits (persistent)
  float* cOw = smem + tb * 10240 + 6144;   // 32x64 cS aliased with owS
  float* xcS = smem + tb * 10240 + 8192;   // 32x64

  // cross-b views for ow / fwv phases
  float* xc0 = smem + 8192;
  float* xc1 = smem + 10240 + 8192;
  float* ow0 = smem + 6144;
  float* ow1 = smem + 10240 + 6144;

  // ---- stage x[b] and rinit ----------------------------------------------
#pragma unroll
  for (int k = 0; k < 4; k++) {
    int lin = tt + 256 * k; int f = lin >> 4; int d0 = (lin & 15) << 2;
    *(float4*)&xs[lidx64(f, d0)] = *(const float4*)(x + b * 4096 + f * 64 + d0);
  }
#pragma unroll
  for (int k = 0; k < 2; k++) {
    int lin = tt + 256 * k; int n = lin >> 4; int f0 = (lin & 15) << 2;
    *(float4*)&bS[lidx64(n, f0)] = *(const float4*)(rinit + n * 64 + f0);
  }
  __syncthreads();

  const int tn = tt >> 4, tlo = tt & 15;
  const int nq = t >> 4, sub = t & 15;     // cross-b mapping: 32 n x 4 cols

  for (int it = 0; it < 4; it++) {
    // ---- cS = softmax over n per f column (per-b) -------------------------
    {
      const int nl = tt & 31, fg = tt >> 5;   // fg 0..7
#pragma unroll
      for (int qq = 0; qq < 2; qq++) {
        const int f0 = (fg * 2 + qq) * 4;
        float v[4];
        *(float4*)v = *(const float4*)&bS[lidx64(nl, f0)];
        float e[4];
#pragma unroll
        for (int j = 0; j < 4; j++) {
          float m = v[j];
          m = fmaxf(m, __shfl_xor(m, 16, 64));
          m = fmaxf(m, __shfl_xor(m, 8, 64));
          m = fmaxf(m, __shfl_xor(m, 4, 64));
          m = fmaxf(m, __shfl_xor(m, 2, 64));
          m = fmaxf(m, __shfl_xor(m, 1, 64));
          e[j] = __expf(v[j] - m);
          float s = e[j];
          s += __shfl_xor(s, 16, 64);
          s += __shfl_xor(s, 8, 64);
          s += __shfl_xor(s, 4, 64);
          s += __shfl_xor(s, 2, 64);
          s += __shfl_xor(s, 1, 64);
          e[j] /= s;
        }
        *(float4*)&cOw[lidx64(nl, f0)] = *(float4*)e;
      }
    }
    __syncthreads();
    if (it == 3) {
#pragma unroll
      for (int k = 0; k < 2; k++) {
        int lin = tt + 256 * k;              // 0..511
        int n = lin >> 4, fq = lin & 15;
        float4 v = *(const float4*)&cOw[lidx64(n, fq * 4)];
        *(float4*)(rs + b * 2048 + n * 64 + fq * 4) = v;
      }
    }
    // ---- xcS = cS . xs (per-b) -------------------------------------------
    {
      const int n0 = tn * 2, d0 = tlo * 4;
      float acc[2][4] = {{0, 0, 0, 0}, {0, 0, 0, 0}};
      for (int fq = 0; fq < 16; fq++) {
        float c0[4], c1[4];
        *(float4*)c0 = *(const float4*)&cOw[lidx64(n0, fq * 4)];
        *(float4*)c1 = *(const float4*)&cOw[lidx64(n0 + 1, fq * 4)];
#pragma unroll
        for (int j = 0; j < 4; j++) {
          float xr[4];
          *(float4*)xr = *(const float4*)&xs[lidx64(fq * 4 + j, d0)];
#pragma unroll
          for (int i = 0; i < 4; i++) {
            acc[0][i] += c0[j] * xr[i];
            acc[1][i] += c1[j] * xr[i];
          }
        }
      }
      *(float4*)&xcS[lidx64(n0, d0)] = *(float4*)acc[0];
      *(float4*)&xcS[lidx64(n0 + 1, d0)] = *(float4*)acc[1];
    }
    __syncthreads();
    if (it == 3) break;

    // ---- ow = scale * (xc . Q_n): CROSS-B, Q streamed once ----------------
    {
      const float* Qn = Qb + nq * 4096 + sub * 4;
      float y0[4] = {}, y1[4] = {};
#pragma unroll 4
      for (int dq = 0; dq < 16; dq++) {
        float xv0[4], xv1[4];
        *(float4*)xv0 = *(const float4*)&xc0[lidx64(nq, dq * 4)];
        *(float4*)xv1 = *(const float4*)&xc1[lidx64(nq, dq * 4)];
#pragma unroll
        for (int j = 0; j < 4; j++) {
          float4 q = *(const float4*)(Qn + (dq * 4 + j) * 64);
          y0[0] += xv0[j] * q.x; y0[1] += xv0[j] * q.y;
          y0[2] += xv0[j] * q.z; y0[3] += xv0[j] * q.w;
          y1[0] += xv1[j] * q.x; y1[1] += xv1[j] * q.y;
          y1[2] += xv1[j] * q.z; y1[3] += xv1[j] * q.w;
        }
      }
      float xa0[4], xa1[4];
      *(float4*)xa0 = *(const float4*)&xc0[lidx64(nq, sub * 4)];
      *(float4*)xa1 = *(const float4*)&xc1[lidx64(nq, sub * 4)];
      float ps0 = y0[0] * xa0[0] + y0[1] * xa0[1] + y0[2] * xa0[2] + y0[3] * xa0[3];
      float ps1 = y1[0] * xa1[0] + y1[1] * xa1[1] + y1[2] * xa1[2] + y1[3] * xa1[3];
      ps0 += __shfl_xor(ps0, 1, 64); ps0 += __shfl_xor(ps0, 2, 64);
      ps0 += __shfl_xor(ps0, 4, 64); ps0 += __shfl_xor(ps0, 8, 64);
      ps1 += __shfl_xor(ps1, 1, 64); ps1 += __shfl_xor(ps1, 2, 64);
      ps1 += __shfl_xor(ps1, 4, 64); ps1 += __shfl_xor(ps1, 8, 64);
      const float ss0 = ps0 + EPS_SQ, ss1 = ps1 + EPS_SQ;
      const float sc0 = sqrtf(ss0) / (0.5f + ss0);
      const float sc1 = sqrtf(ss1) / (0.5f + ss1);
      float o0[4] = {y0[0] * sc0, y0[1] * sc0, y0[2] * sc0, y0[3] * sc0};
      float o1[4] = {y1[0] * sc1, y1[1] * sc1, y1[2] * sc1, y1[3] * sc1};
      *(float4*)&ow0[lidx64(nq, sub * 4)] = *(float4*)o0;
      *(float4*)&ow1[lidx64(nq, sub * 4)] = *(float4*)o1;
    }
    __syncthreads();

    // ---- bS += xs . owS^T (per-b) ----------------------------------------
    {
      const int n0 = tn * 2, f0 = tlo * 4;
      float acc[2][4] = {{0, 0, 0, 0}, {0, 0, 0, 0}};
      for (int dq = 0; dq < 64; dq += 4) {
        float o[2][4];
        *(float4*)o[0] = *(const float4*)&cOw[lidx64(n0, dq)];
        *(float4*)o[1] = *(const float4*)&cOw[lidx64(n0 + 1, dq)];
#pragma unroll
        for (int i = 0; i < 4; i++) {
          float xr[4];
          *(float4*)xr = *(const float4*)&xs[lidx64(f0 + i, dq)];
#pragma unroll
          for (int k = 0; k < 4; k++) {
            acc[0][i] += o[0][k] * xr[k];
            acc[1][i] += o[1][k] * xr[k];
          }
        }
      }
#pragma unroll
      for (int j = 0; j < 2; j++) {
        float tmp[4];
        *(float4*)tmp = *(const float4*)&bS[lidx64(n0 + j, f0)];
#pragma unroll
        for (int i = 0; i < 4; i++) tmp[i] += acc[j][i];
        *(float4*)&bS[lidx64(n0 + j, f0)] = *(float4*)tmp;
      }
    }
    __syncthreads();
  }

  // ---- fwv = xcS . W: CROSS-B, W streamed once ----------------------------
  {
    const float* Wn = W + nq * 64 + sub * 4;
    float a0[4] = {}, a1[4] = {};
#pragma unroll 4
    for (int dq = 0; dq < 16; dq++) {
      float xv0[4], xv1[4];
      *(float4*)xv0 = *(const float4*)&xc0[lidx64(nq, dq * 4)];
      *(float4*)xv1 = *(const float4*)&xc1[lidx64(nq, dq * 4)];
#pragma unroll
      for (int j = 0; j < 4; j++) {
        float4 w = *(const float4*)(Wn + (dq * 4 + j) * 2048);
        a0[0] += xv0[j] * w.x; a0[1] += xv0[j] * w.y;
        a0[2] += xv0[j] * w.z; a0[3] += xv0[j] * w.w;
        a1[0] += xv1[j] * w.x; a1[1] += xv1[j] * w.y;
        a1[2] += xv1[j] * w.z; a1[3] += xv1[j] * w.w;
      }
    }
    const int b0g = blockIdx.x * 2;
    *(float4*)(fwv + b0g * 2048 + nq * 64 + sub * 4) = *(float4*)a0;
    *(float4*)(fwv + (b0g + 1) * 2048 + nq * 64 + sub * 4) = *(float4*)a1;
  }
}

// ---------------------------------------------------------------------------
// k_attn2: FUSED ih + attn, one block per b.
//   Phase I (ih): xB/cF2 staged into dead pS/bufA regions; per-wave MFMA ssq
//   for 8 n's (bit-identical to old k_ih); ssqS in tS region; FM partial p
//   folded into a register. Phase II: attn body verbatim R13.
// ---------------------------------------------------------------------------
__global__ __launch_bounds__(256, 4) void k_attn2(
    const float* __restrict__ fwv, const float* __restrict__ x,
    const unsigned short* __restrict__ Wbf, const float* __restrict__ rs,
    const float* __restrict__ Ab, const float* __restrict__ Kb,
    const float* __restrict__ Wv, const float* __restrict__ Wr,
    const float* __restrict__ kfm, const float* __restrict__ bfm,
    const float* __restrict__ bmf, const float* __restrict__ khi,
    const float* __restrict__ bhi, float* __restrict__ out0)
{
  __shared__ __align__(16) float smem[8832];   // 35328 B
  float* fwS  = smem;               // 32x68 (2176 f)
  float* pS   = smem + 2176;        // 64x36 (2304 f)
  float* bufA = smem + 4480;        // 32x68 (2176 f)
  float* tS   = smem + 6656;        // 32x68 (2176 f); uS; ssqS in phase I
  float* vS   = smem + 4480;        // 32x132 (4224 f) (alias)
  float* redH = smem + 2176;        // 16x132 (alias of pS)
  float* Kf   = smem + 4480;        // 32x33 padded (alias, post-vS)
  float* red1 = smem + 5536;        // 8x68
  // phase-I aliases (all dead before their regions are reused):
  unsigned short* xB   = (unsigned short*)(smem + 2176);  // 2048 f (pS)
  unsigned short* cF2s = (unsigned short*)(smem + 4480);  // 1024 f (bufA)
  float*          ssqS = smem + 6656;                     // 2048 f (tS)

  const int b = blockIdx.x, t = threadIdx.x;
  const int tn = t >> 4, te = t & 15;
  const int n0 = tn * 2, e0 = te * 8, d0 = te * 4;
  const int w = t >> 6, lane = t & 63;

  // ---- stage fwS + xB(bf16 x) + cF2(bf16 c^2) -----------------------------
#pragma unroll
  for (int k = 0; k < 2; k++) {
    int lin = t + 256 * k; int nn = lin >> 4; int c0 = (lin & 15) << 2;
    *(float4*)&fwS[lidx(nn, c0)] = *(const float4*)(fwv + b * 2048 + nn * 64 + c0);
  }
#pragma unroll
  for (int k = 0; k < 4; k++) {
    int ch = t + 256 * k;            // 0..1023 = 64 f x 16 fq
    int f = ch >> 4, fq = ch & 15;
    int dg = fq >> 1, half = fq & 1;
    float4 v = *(const float4*)(x + (b * 64 + f) * 64 + fq * 4);
    unsigned p0 = f2bf(v.x) | ((unsigned)f2bf(v.y) << 16);
    unsigned p1 = f2bf(v.z) | ((unsigned)f2bf(v.w) << 16);
    *(uint2*)&xB[f * 64 + ((dg ^ (f & 7)) << 3) + half * 4] = make_uint2(p0, p1);
  }
#pragma unroll
  for (int k = 0; k < 2; k++) {
    int lin = t + 256 * k;           // 0..511 = 32 n x 16 fq
    int n = lin >> 4, f0 = (lin & 15) << 2;
    float4 v = *(const float4*)(rs + b * 2048 + n * 64 + f0);
    unsigned short t4[4] = {f2bf(v.x * v.x), f2bf(v.y * v.y),
                            f2bf(v.z * v.z), f2bf(v.w * v.w)};
    *(uint2*)&cF2s[n * 64 + f0] = *(uint2*)t4;
  }
  __syncthreads();

  // ---- phase I: ssq via MFMA; wave w handles n in [w*8, w*8+8) ------------
  {
    const int m = lane & 15, q = lane >> 4, ms = m & 7;
    bf16x8 a_[4][2];
#pragma unroll
    for (int mi = 0; mi < 4; mi++) {
      const unsigned short* bp = xB + (mi * 16 + m) * 64;
#pragma unroll
      for (int kk = 0; kk < 2; kk++)
        a_[mi][kk] = *(const bf16x8*)&bp[((kk * 4 + q) ^ ms) << 3];
    }
#pragma unroll 2
    for (int nn = 0; nn < 8; nn++) {
      const int n = w * 8 + nn;
      bf16x8 bf[4][2];
#pragma unroll
      for (int ci = 0; ci < 4; ci++) {
        const unsigned short* bp = Wbf + n * 4096 + (ci * 16 + m) * 64;
#pragma unroll
        for (int kk = 0; kk < 2; kk++)
          bf[ci][kk] = *(const bf16x8*)&bp[((kk * 4 + q) ^ ms) << 3];
      }
      float ps[4] = {0.f, 0.f, 0.f, 0.f};
      const unsigned short* cf = cF2s + n * 64 + q * 4;
#pragma unroll
      for (int mi = 0; mi < 4; mi++) {
        float cfv[4];
#pragma unroll
        for (int r = 0; r < 4; r++)
          cfv[r] = __uint_as_float((unsigned)cf[mi * 16 + r] << 16);
#pragma unroll
        for (int ci = 0; ci < 4; ci++) {
          floatx4 c0 = {0.f, 0.f, 0.f, 0.f};
          c0 = __builtin_amdgcn_mfma_f32_16x16x32_bf16(a_[mi][0], bf[ci][0], c0, 0, 0, 0);
          c0 = __builtin_amdgcn_mfma_f32_16x16x32_bf16(a_[mi][1], bf[ci][1], c0, 0, 0, 0);
#pragma unroll
          for (int r = 0; r < 4; r++) { float tv = c0[r]; ps[ci] += cfv[r] * tv * tv; }
        }
      }
#pragma unroll
      for (int ci = 0; ci < 4; ci++) {
        ps[ci] += __shfl_xor(ps[ci], 16, 64);
        ps[ci] += __shfl_xor(ps[ci], 32, 64);
      }
      if (q == 0) {
#pragma unroll
        for (int ci = 0; ci < 4; ci++)
          ssqS[n * 64 + ci * 16 + m] = ps[ci];
      }
    }
  }
  __syncthreads();

  // ---- FM partial into a register (same order as old tail) ----------------
  float p_reg = 0.f;
  {
    const int c = t & 63, nqf = t >> 6;
#pragma unroll
    for (int k = 0; k < 8; k++) {
      int nn = nqf * 8 + k;
      float fv = fwS[lidx(nn, c)];
      float sv = ssqS[nn * 64 + c];
      p_reg += (fv * fv - sv) * kfm[nn];
    }
  }
  __syncthreads();

  // ---- phase II: attn body (R13 verbatim) ---------------------------------
  for (int h = 0; h < 2; h++) {
    float tacc[2][4] = {};
    for (int half = 0; half < 2; half++) {
#pragma unroll
      for (int k = 0; k < 2; k++) {
        int lin = t + 256 * k; int d = lin >> 4; int c0 = (lin & 15) << 2;
        *(float4*)&bufA[lidx(d, c0)] =
            *(const float4*)(Ab + h * 4096 + (half * 32 + d) * 64 + c0);
      }
      __syncthreads();
      for (int dq = 0; dq < 32; dq += 4) {
        float fw0[4], fw1[4];
        *(float4*)fw0 = *(const float4*)&fwS[lidx(n0, half * 32 + dq)];
        *(float4*)fw1 = *(const float4*)&fwS[lidx(n0 + 1, half * 32 + dq)];
#pragma unroll
        for (int j = 0; j < 4; j++) {
          float mr[4];
          *(float4*)mr = *(const float4*)&bufA[lidx(dq + j, d0)];
#pragma unroll
          for (int c = 0; c < 4; c++) {
            tacc[0][c] += fw0[j] * mr[c];
            tacc[1][c] += fw1[j] * mr[c];
          }
        }
      }
      __syncthreads();
    }
    *(float4*)&tS[lidx(n0, d0)] = *(float4*)tacc[0];
    *(float4*)&tS[lidx(n0 + 1, d0)] = *(float4*)tacc[1];
    __syncthreads();
    {
      const int m0 = te * 2;
      float s00 = 0.f, s01 = 0.f, s10 = 0.f, s11 = 0.f;
      for (int kk = 0; kk < 16; kk++) {
        float ta0[4], ta1[4], f0[4], f1[4];
        *(float4*)ta0 = *(const float4*)&tS[lidx(n0, kk * 4)];
        *(float4*)ta1 = *(const float4*)&tS[lidx(n0 + 1, kk * 4)];
        *(float4*)f0 = *(const float4*)&fwS[lidx(m0, kk * 4)];
        *(float4*)f1 = *(const float4*)&fwS[lidx(m0 + 1, kk * 4)];
#pragma unroll
        for (int j = 0; j < 4; j++) {
          s00 += ta0[j] * f0[j]; s01 += ta0[j] * f1[j];
          s10 += ta1[j] * f0[j]; s11 += ta1[j] * f1[j];
        }
      }
      pS[(h * 32 + n0) * 36 + m0] = s00;
      pS[(h * 32 + n0) * 36 + m0 + 1] = s01;
      pS[(h * 32 + n0 + 1) * 36 + m0] = s10;
      pS[(h * 32 + n0 + 1) * 36 + m0 + 1] = s11;
    }
    __syncthreads();
  }

  {
    const int r = t >> 2, sub = t & 3;
    const int base = r * 36 + sub * 8;
    float v0[4], v1[4];
    *(float4*)v0 = *(const float4*)&pS[base];
    *(float4*)v1 = *(const float4*)&pS[base + 4];
    float mx = fmaxf(fmaxf(fmaxf(v0[0], v0[1]), fmaxf(v0[2], v0[3])),
                     fmaxf(fmaxf(v1[0], v1[1]), fmaxf(v1[2], v1[3])));
    mx = fmaxf(mx, __shfl_xor(mx, 1, 64));
    mx = fmaxf(mx, __shfl_xor(mx, 2, 64));
    float sum = 0.f;
#pragma unroll
    for (int j = 0; j < 4; j++) { v0[j] = __expf(v0[j] - mx); sum += v0[j]; }
#pragma unroll
    for (int j = 0; j < 4; j++) { v1[j] = __expf(v1[j] - mx); sum += v1[j]; }
    sum += __shfl_xor(sum, 1, 64);
    sum += __shfl_xor(sum, 2, 64);
    const float inv = 1.0f / sum;
#pragma unroll
    for (int j = 0; j < 4; j++) { v0[j] *= inv; v1[j] *= inv; }
    *(float4*)&pS[base] = *(float4*)v0;
    *(float4*)&pS[base + 4] = *(float4*)v1;
  }
  __syncthreads();

  {
    float acc[2][8] = {};
    for (int dq = 0; dq < 64; dq += 4) {
      float fw0[4], fw1[4];
      *(float4*)fw0 = *(const float4*)&fwS[lidx(n0, dq)];
      *(float4*)fw1 = *(const float4*)&fwS[lidx(n0 + 1, dq)];
#pragma unroll
      for (int jj = 0; jj < 4; jj++) {
        float w8[8];
        *(float4*)&w8[0] = *(const float4*)(Wv + (dq + jj) * 128 + e0);
        *(float4*)&w8[4] = *(const float4*)(Wv + (dq + jj) * 128 + e0 + 4);
#pragma unroll
        for (int j = 0; j < 8; j++) {
          acc[0][j] += fw0[jj] * w8[j];
          acc[1][j] += fw1[jj] * w8[j];
        }
      }
    }
    *(float4*)&vS[n0 * 132 + e0] = *(float4*)&acc[0][0];
    *(float4*)&vS[n0 * 132 + e0 + 4] = *(float4*)&acc[0][4];
    *(float4*)&vS[(n0 + 1) * 132 + e0] = *(float4*)&acc[1][0];
    *(float4*)&vS[(n0 + 1) * 132 + e0 + 4] = *(float4*)&acc[1][4];
  }
  __syncthreads();

  {
    const int h2 = te >> 3;
    float pacc[2][8] = {};
    for (int m4 = 0; m4 < 8; m4++) {
      float p0v[4], p1v[4];
      *(float4*)p0v = *(const float4*)&pS[(h2 * 32 + n0) * 36 + m4 * 4];
      *(float4*)p1v = *(const float4*)&pS[(h2 * 32 + n0 + 1) * 36 + m4 * 4];
#pragma unroll
      for (int mm = 0; mm < 4; mm++) {
        const int m = m4 * 4 + mm;
        float vr[8];
        *(float4*)&vr[0] = *(const float4*)&vS[m * 132 + e0];
        *(float4*)&vr[4] = *(const float4*)&vS[m * 132 + e0 + 4];
#pragma unroll
        for (int j = 0; j < 8; j++) {
          pacc[0][j] += p0v[mm] * vr[j];
          pacc[1][j] += p1v[mm] * vr[j];
        }
      }
    }
    for (int dq = 0; dq < 64; dq += 4) {
      float fw0[4], fw1[4];
      *(float4*)fw0 = *(const float4*)&fwS[lidx(n0, dq)];
      *(float4*)fw1 = *(const float4*)&fwS[lidx(n0 + 1, dq)];
#pragma unroll
      for (int jj = 0; jj < 4; jj++) {
        float w8[8];
        *(float4*)&w8[0] = *(const float4*)(Wr + (dq + jj) * 128 + e0);
        *(float4*)&w8[4] = *(const float4*)(Wr + (dq + jj) * 128 + e0 + 4);
#pragma unroll
        for (int j = 0; j < 8; j++) {
          pacc[0][j] += fw0[jj] * w8[j];
          pacc[1][j] += fw1[jj] * w8[j];
        }
      }
    }
    __syncthreads();
    {
      float kh0 = khi[n0], kh1 = khi[n0 + 1];
      float ph[8];
#pragma unroll
      for (int j = 0; j < 8; j++)
        ph[j] = kh0 * fmaxf(pacc[0][j], 0.f) + kh1 * fmaxf(pacc[1][j], 0.f);
      *(float4*)&redH[tn * 132 + e0] = *(float4*)&ph[0];
      *(float4*)&redH[tn * 132 + e0 + 4] = *(float4*)&ph[4];
    }
  }
  // ---- stage Kf with 33-stride pad ----------------------------------------
  {
    const int p4 = t * 4;
    float4 kv = *(const float4*)(Kb + p4);
    const int n = p4 >> 5, r = p4 & 31;
    Kf[n * 33 + r]     = kv.x;
    Kf[n * 33 + r + 1] = kv.y;
    Kf[n * 33 + r + 2] = kv.z;
    Kf[n * 33 + r + 3] = kv.w;
  }
  __syncthreads();

  // ---- MF stage A: u = Kf . fwS  (into uS = tS region, dead) --------------
  {
    float acc[2][4] = {{0, 0, 0, 0}, {0, 0, 0, 0}};
    for (int r = 0; r < 32; r++) {
      const float k0 = Kf[n0 * 33 + r];
      const float k1 = Kf[(n0 + 1) * 33 + r];
      float fr[4];
      *(float4*)fr = *(const float4*)&fwS[lidx(r, d0)];
#pragma unroll
      for (int i = 0; i < 4; i++) {
        acc[0][i] += k0 * fr[i];
        acc[1][i] += k1 * fr[i];
      }
    }
    *(float4*)&tS[lidx(n0, d0)] = *(float4*)acc[0];
    *(float4*)&tS[lidx(n0 + 1, d0)] = *(float4*)acc[1];
  }
  __syncthreads();

  if (t < 128) {
    float s = 0.f;
#pragma unroll
    for (int k = 0; k < 16; k++) s += redH[k * 132 + t];
    out0[b * 256 + 128 + t] = s + bhi[t];
  }
  {
    const int c = t & 63, nq = t >> 6;
    red1[nq * 68 + c] = p_reg;
    // MF stage B: hmf = sum_l fw[l,c] * u[l,c] over this nq's 8 rows
    float hmf = 0.f;
#pragma unroll
    for (int l8 = 0; l8 < 8; l8++) {
      const int l = nq * 8 + l8;
      hmf += fwS[lidx(l, c)] * tS[lidx(l, c)];
    }
    red1[(4 + nq) * 68 + c] = hmf;
  }
  __syncthreads();
  if (t < 64) {
    out0[b * 256 + t] = red1[t] + red1[68 + t] + red1[136 + t] + red1[204 + t] + bfm[t];
    float h2 = red1[272 + t] + red1[340 + t] + red1[408 + t] + red1[476 + t];
    out0[b * 256 + 64 + t] = 0.5f * h2 + bmf[t];
  }
}

// ---------------------------------------------------------------------------
extern "C" void kernel_launch(void* const* d_in, const int* in_sizes, int n_in,
                              void* d_out, int out_size, void* d_ws, size_t ws_size,
                              hipStream_t stream) {
  (void)in_sizes; (void)n_in; (void)out_size; (void)ws_size;
  const float* x     = (const float*)d_in[0];
  const float* W     = (const float*)d_in[1];
  const float* rinit = (const float*)d_in[2];
  const float* kfm   = (const float*)d_in[3];
  const float* bfm   = (const float*)d_in[4];
  const float* kmf   = (const float*)d_in[5];
  const float* bmf   = (const float*)d_in[6];
  const float* khi   = (const float*)d_in[7];
  const float* bhi   = (const float*)d_in[8];
  const float* Wq    = (const float*)d_in[9];
  const float* Wk    = (const float*)d_in[10];
  const float* Wv    = (const float*)d_in[11];
  const float* Wr    = (const float*)d_in[12];

  float* out0 = (float*)d_out;
  float* rs   = out0 + 1024 * 256;  // routing_score [B,32,64,1]

  float* ws   = (float*)d_ws;       // 24 MB
  float* Abuf = ws;                 // [2][64][64] = 8192 f
  float* Kbuf = ws + 8192;          // [32][32]    = 1024 f
  float* Qbuf = ws + 16384;         // [32][64][64] = 131072 f
  unsigned short* Wbf = (unsigned short*)(ws + 262144);  // [32][4096] bf16
  float* fwv  = ws + 2097152;       // [B,32,64]

  k_prep2<<<73, 256, 0, stream>>>(W, Wq, Wk, kmf, Qbuf, Abuf, Kbuf, Wbf);
  k_route3<<<512, 512, 0, stream>>>(x, W, rinit, Qbuf, rs, fwv);
  k_attn2<<<1024, 256, 0, stream>>>(fwv, x, Wbf, rs, Abuf, Kbuf, Wv, Wr,
                                    kfm, bfm, bmf, khi, bhi, out0);
}

// Round 9
// 256.243 us; speedup vs baseline: 1.0324x; 1.0324x over previous
//
#include <hip/hip_runtime.h>

// CapsuleLayer fused pipeline, round 16.
//  - R15 POST-MORTEM: route3 measured 113.9us with R13-VERBATIM code (98.5 in
//    R6 run): hbm_gbps 847 vs 990 = ~15% clock-state difference, not code.
//    Non-route time 150.7 vs 153.7 -> fusion was a small win; KEPT.
//    Lesson: only attribute deltas >=10% of a kernel; normalize by clock.
//  - R14 decomposition: no-max softmax (-40 ds_swizzle/thread/iter on the
//    dominant LDS pipe, ~-10us) + 128-thread tiling (-20us REGRESSION).
//    R14 PASSED with absmax 0.125 -> no-max is tolerance-safe.
//  - R16: no-max softmax ONLY, in the R13 route structure (256 thr/b).
//    Shift-invariant exact math; |logit|<=~30, exp<=1e13, fp32-safe.
//    Predicted: route -9-11% clock-normalized, absmax 0.125.
//  - k_prep2 / k_attn2 unchanged (R15).
//  - NO cooperative launches (R6 lesson: harness graph capture fails).

#define EPS_SQ 1e-7f

typedef __attribute__((ext_vector_type(8))) short bf16x8;
typedef __attribute__((ext_vector_type(4))) float floatx4;

__device__ __forceinline__ int lidx(int r, int c) {
  // 64-col fp32 tile, row stride 68 dwords, quad-swizzle (legacy kernels)
  return r * 68 + ((((c >> 2) ^ (r >> 2)) & 15) << 2) + (c & 3);
}
__device__ __forceinline__ int lidx64(int r, int c) {
  // unpadded 64-col fp32 tile, XOR swizzle at float4 granularity.
  // R10: include r>>2 so rows stepping by 4 rotate bank-quads.
  return r * 64 + ((((c >> 2) ^ r ^ (r >> 2)) & 15) << 2) + (c & 3);
}
__device__ __forceinline__ unsigned short f2bf(float f) {
  unsigned u = __float_as_uint(f);
  u += 0x7FFFu + ((u >> 16) & 1u);   // RNE
  return (unsigned short)(u >> 16);
}

// ---------------------------------------------------------------------------
// k_prep2: bid<32: Q_n = M_n.M_n^T ; bid 32..39: A_h = Wq_h.Wk_h^T ;
//          bid 40: symmetric pair matrix K from kmf ;
//          bid 41..72: Wbf = W in bf16 MFMA-B-fragment layout.
// ---------------------------------------------------------------------------
__global__ __launch_bounds__(256) void k_prep2(
    const float* __restrict__ W, const float* __restrict__ Wq,
    const float* __restrict__ Wk, const float* __restrict__ kmf,
    float* __restrict__ Qb, float* __restrict__ Ab, float* __restrict__ Kb,
    unsigned short* __restrict__ Wbf)
{
  const int t = threadIdx.x;
  if (blockIdx.x < 32) {
    __shared__ __align__(16) float Mn[64 * 68];
    const int n = blockIdx.x;
#pragma unroll
    for (int k = 0; k < 4; k++) {
      int lin = t + 256 * k; int d = lin >> 4; int c0 = (lin & 15) << 2;
      *(float4*)&Mn[lidx(d, c0)] = *(const float4*)(W + d * 2048 + n * 64 + c0);
    }
    __syncthreads();
    const int d1 = (t >> 4) * 4, d2 = (t & 15) * 4;
    float acc[4][4] = {};
    for (int cq = 0; cq < 64; cq += 4) {
      float m1[4][4], m2[4][4];
#pragma unroll
      for (int i = 0; i < 4; i++) *(float4*)m1[i] = *(const float4*)&Mn[lidx(d1 + i, cq)];
#pragma unroll
      for (int j = 0; j < 4; j++) *(float4*)m2[j] = *(const float4*)&Mn[lidx(d2 + j, cq)];
#pragma unroll
      for (int i = 0; i < 4; i++)
#pragma unroll
        for (int j = 0; j < 4; j++) {
          float s = 0.f;
#pragma unroll
          for (int k = 0; k < 4; k++) s += m1[i][k] * m2[j][k];
          acc[i][j] += s;
        }
    }
#pragma unroll
    for (int i = 0; i < 4; i++)
      *(float4*)(Qb + n * 4096 + (d1 + i) * 64 + d2) = *(float4*)acc[i];
  } else if (blockIdx.x < 40) {
    __shared__ __align__(16) float wkS[64 * 68];
    __shared__ __align__(16) float wqS[16 * 68];
    const int hb = blockIdx.x - 32;
    const int h = hb & 1, rg = hb >> 1;
#pragma unroll
    for (int k = 0; k < 4; k++) {
      int lin = t + 256 * k; int dp = lin >> 4; int e0 = (lin & 15) << 2;
      *(float4*)&wkS[lidx(dp, e0)] = *(const float4*)(Wk + dp * 128 + h * 64 + e0);
    }
    {
      int dl = t >> 4, e0 = (t & 15) << 2;
      *(float4*)&wqS[lidx(dl, e0)] = *(const float4*)(Wq + (rg * 16 + dl) * 128 + h * 64 + e0);
    }
    __syncthreads();
    const int dl = t >> 4, dp0 = (t & 15) << 2;
    float acc[4] = {};
    for (int e = 0; e < 64; e += 4) {
      float q4[4];
      *(float4*)q4 = *(const float4*)&wqS[lidx(dl, e)];
#pragma unroll
      for (int c = 0; c < 4; c++) {
        float mr[4];
        *(float4*)mr = *(const float4*)&wkS[lidx(dp0 + c, e)];
        acc[c] += q4[0] * mr[0] + q4[1] * mr[1] + q4[2] * mr[2] + q4[3] * mr[3];
      }
    }
    *(float4*)(Ab + h * 4096 + (rg * 16 + dl) * 64 + dp0) = *(float4*)acc;
  } else if (blockIdx.x == 40) {
    __shared__ float Ks[1024];
    *(float4*)&Ks[t * 4] = make_float4(0.f, 0.f, 0.f, 0.f);
    __syncthreads();
    if (t < 248) {
#pragma unroll
      for (int j = 0; j < 2; j++) {
        int p = t * 2 + j;
        if (p < 496) {
          int l = 0, rem = p;
          while (rem >= 31 - l) { rem -= 31 - l; ++l; }
          int r = l + 1 + rem;
          float v = kmf[p];
          Ks[l * 32 + r] = v;
          Ks[r * 32 + l] = v;
        }
      }
    }
    __syncthreads();
    *(float4*)&Kb[t * 4] = *(const float4*)&Ks[t * 4];
  } else {
    // Wbf: per n, element (c,d) at Wbf[n*4096 + c*64 + ((dg^(c&7))<<3) + dl],
    // dg=d>>3, dl=d&7 -- the exact wB layout the old k_ih built per-block.
    const int n = blockIdx.x - 41;
#pragma unroll
    for (int k = 0; k < 2; k++) {
      int lin = t + 256 * k;          // 0..511 = 64 c x 8 dg
      int c = lin >> 3, dg = lin & 7;
      unsigned short tmp[8];
#pragma unroll
      for (int dl = 0; dl < 8; dl++)
        tmp[dl] = f2bf(W[(dg * 8 + dl) * 2048 + n * 64 + c]);
      *(uint4*)&Wbf[n * 4096 + c * 64 + ((dg ^ (c & 7)) << 3)] = *(uint4*)tmp;
    }
  }
}

// ---------------------------------------------------------------------------
// k_route3: routing for TWO b's per 512-thread block.
//   R16: no-max softmax (only change vs R13).
// ---------------------------------------------------------------------------
__global__ __launch_bounds__(512, 4) void k_route3(
    const float* __restrict__ x, const float* __restrict__ W,
    const float* __restrict__ rinit, const float* __restrict__ Qb,
    float* __restrict__ rs, float* __restrict__ fwv)
{
  __shared__ __align__(16) float smem[2 * 10240];   // 81920 B exactly

  const int t = threadIdx.x;
  const int tb = t >> 8, tt = t & 255;
  const int b = blockIdx.x * 2 + tb;

  float* xs  = smem + tb * 10240;          // 64x64 (swizzled)
  float* bS  = smem + tb * 10240 + 4096;   // 32x64 logits (persistent)
  float* cOw = smem + tb * 10240 + 6144;   // 32x64 cS aliased with owS
  float* xcS = smem + tb * 10240 + 8192;   // 32x64

  // cross-b views for ow / fwv phases
  float* xc0 = smem + 8192;
  float* xc1 = smem + 10240 + 8192;
  float* ow0 = smem + 6144;
  float* ow1 = smem + 10240 + 6144;

  // ---- stage x[b] and rinit ----------------------------------------------
#pragma unroll
  for (int k = 0; k < 4; k++) {
    int lin = tt + 256 * k; int f = lin >> 4; int d0 = (lin & 15) << 2;
    *(float4*)&xs[lidx64(f, d0)] = *(const float4*)(x + b * 4096 + f * 64 + d0);
  }
#pragma unroll
  for (int k = 0; k < 2; k++) {
    int lin = tt + 256 * k; int n = lin >> 4; int f0 = (lin & 15) << 2;
    *(float4*)&bS[lidx64(n, f0)] = *(const float4*)(rinit + n * 64 + f0);
  }
  __syncthreads();

  const int tn = tt >> 4, tlo = tt & 15;
  const int nq = t >> 4, sub = t & 15;     // cross-b mapping: 32 n x 4 cols

  for (int it = 0; it < 4; it++) {
    // ---- cS = softmax over n per f column (per-b), NO max-subtract --------
    // exact math: softmax is shift-invariant; |logit| <= ~30 -> exp <= 1e13,
    // safely inside fp32 range. R14 verified absmax 0.125 passes.
    {
      const int nl = tt & 31, fg = tt >> 5;   // fg 0..7
#pragma unroll
      for (int qq = 0; qq < 2; qq++) {
        const int f0 = (fg * 2 + qq) * 4;
        float v[4];
        *(float4*)v = *(const float4*)&bS[lidx64(nl, f0)];
        float e[4];
#pragma unroll
        for (int j = 0; j < 4; j++) {
          e[j] = __expf(v[j]);
          float s = e[j];
          s += __shfl_xor(s, 16, 64);
          s += __shfl_xor(s, 8, 64);
          s += __shfl_xor(s, 4, 64);
          s += __shfl_xor(s, 2, 64);
          s += __shfl_xor(s, 1, 64);
          e[j] /= s;
        }
        *(float4*)&cOw[lidx64(nl, f0)] = *(float4*)e;
      }
    }
    __syncthreads();
    if (it == 3) {
#pragma unroll
      for (int k = 0; k < 2; k++) {
        int lin = tt + 256 * k;              // 0..511
        int n = lin >> 4, fq = lin & 15;
        float4 v = *(const float4*)&cOw[lidx64(n, fq * 4)];
        *(float4*)(rs + b * 2048 + n * 64 + fq * 4) = v;
      }
    }
    // ---- xcS = cS . xs (per-b) -------------------------------------------
    {
      const int n0 = tn * 2, d0 = tlo * 4;
      float acc[2][4] = {{0, 0, 0, 0}, {0, 0, 0, 0}};
      for (int fq = 0; fq < 16; fq++) {
        float c0[4], c1[4];
        *(float4*)c0 = *(const float4*)&cOw[lidx64(n0, fq * 4)];
        *(float4*)c1 = *(const float4*)&cOw[lidx64(n0 + 1, fq * 4)];
#pragma unroll
        for (int j = 0; j < 4; j++) {
          float xr[4];
          *(float4*)xr = *(const float4*)&xs[lidx64(fq * 4 + j, d0)];
#pragma unroll
          for (int i = 0; i < 4; i++) {
            acc[0][i] += c0[j] * xr[i];
            acc[1][i] += c1[j] * xr[i];
          }
        }
      }
      *(float4*)&xcS[lidx64(n0, d0)] = *(float4*)acc[0];
      *(float4*)&xcS[lidx64(n0 + 1, d0)] = *(float4*)acc[1];
    }
    __syncthreads();
    if (it == 3) break;

    // ---- ow = scale * (xc . Q_n): CROSS-B, Q streamed once ----------------
    {
      const float* Qn = Qb + nq * 4096 + sub * 4;
      float y0[4] = {}, y1[4] = {};
#pragma unroll 4
      for (int dq = 0; dq < 16; dq++) {
        float xv0[4], xv1[4];
        *(float4*)xv0 = *(const float4*)&xc0[lidx64(nq, dq * 4)];
        *(float4*)xv1 = *(const float4*)&xc1[lidx64(nq, dq * 4)];
#pragma unroll
        for (int j = 0; j < 4; j++) {
          float4 q = *(const float4*)(Qn + (dq * 4 + j) * 64);
          y0[0] += xv0[j] * q.x; y0[1] += xv0[j] * q.y;
          y0[2] += xv0[j] * q.z; y0[3] += xv0[j] * q.w;
          y1[0] += xv1[j] * q.x; y1[1] += xv1[j] * q.y;
          y1[2] += xv1[j] * q.z; y1[3] += xv1[j] * q.w;
        }
      }
      float xa0[4], xa1[4];
      *(float4*)xa0 = *(const float4*)&xc0[lidx64(nq, sub * 4)];
      *(float4*)xa1 = *(const float4*)&xc1[lidx64(nq, sub * 4)];
      float ps0 = y0[0] * xa0[0] + y0[1] * xa0[1] + y0[2] * xa0[2] + y0[3] * xa0[3];
      float ps1 = y1[0] * xa1[0] + y1[1] * xa1[1] + y1[2] * xa1[2] + y1[3] * xa1[3];
      ps0 += __shfl_xor(ps0, 1, 64); ps0 += __shfl_xor(ps0, 2, 64);
      ps0 += __shfl_xor(ps0, 4, 64); ps0 += __shfl_xor(ps0, 8, 64);
      ps1 += __shfl_xor(ps1, 1, 64); ps1 += __shfl_xor(ps1, 2, 64);
      ps1 += __shfl_xor(ps1, 4, 64); ps1 += __shfl_xor(ps1, 8, 64);
      const float ss0 = ps0 + EPS_SQ, ss1 = ps1 + EPS_SQ;
      const float sc0 = sqrtf(ss0) / (0.5f + ss0);
      const float sc1 = sqrtf(ss1) / (0.5f + ss1);
      float o0[4] = {y0[0] * sc0, y0[1] * sc0, y0[2] * sc0, y0[3] * sc0};
      float o1[4] = {y1[0] * sc1, y1[1] * sc1, y1[2] * sc1, y1[3] * sc1};
      *(float4*)&ow0[lidx64(nq, sub * 4)] = *(float4*)o0;
      *(float4*)&ow1[lidx64(nq, sub * 4)] = *(float4*)o1;
    }
    __syncthreads();

    // ---- bS += xs . owS^T (per-b) ----------------------------------------
    {
      const int n0 = tn * 2, f0 = tlo * 4;
      float acc[2][4] = {{0, 0, 0, 0}, {0, 0, 0, 0}};
      for (int dq = 0; dq < 64; dq += 4) {
        float o[2][4];
        *(float4*)o[0] = *(const float4*)&cOw[lidx64(n0, dq)];
        *(float4*)o[1] = *(const float4*)&cOw[lidx64(n0 + 1, dq)];
#pragma unroll
        for (int i = 0; i < 4; i++) {
          float xr[4];
          *(float4*)xr = *(const float4*)&xs[lidx64(f0 + i, dq)];
#pragma unroll
          for (int k = 0; k < 4; k++) {
            acc[0][i] += o[0][k] * xr[k];
            acc[1][i] += o[1][k] * xr[k];
          }
        }
      }
#pragma unroll
      for (int j = 0; j < 2; j++) {
        float tmp[4];
        *(float4*)tmp = *(const float4*)&bS[lidx64(n0 + j, f0)];
#pragma unroll
        for (int i = 0; i < 4; i++) tmp[i] += acc[j][i];
        *(float4*)&bS[lidx64(n0 + j, f0)] = *(float4*)tmp;
      }
    }
    __syncthreads();
  }

  // ---- fwv = xcS . W: CROSS-B, W streamed once ----------------------------
  {
    const float* Wn = W + nq * 64 + sub * 4;
    float a0[4] = {}, a1[4] = {};
#pragma unroll 4
    for (int dq = 0; dq < 16; dq++) {
      float xv0[4], xv1[4];
      *(float4*)xv0 = *(const float4*)&xc0[lidx64(nq, dq * 4)];
      *(float4*)xv1 = *(const float4*)&xc1[lidx64(nq, dq * 4)];
#pragma unroll
      for (int j = 0; j < 4; j++) {
        float4 w = *(const float4*)(Wn + (dq * 4 + j) * 2048);
        a0[0] += xv0[j] * w.x; a0[1] += xv0[j] * w.y;
        a0[2] += xv0[j] * w.z; a0[3] += xv0[j] * w.w;
        a1[0] += xv1[j] * w.x; a1[1] += xv1[j] * w.y;
        a1[2] += xv1[j] * w.z; a1[3] += xv1[j] * w.w;
      }
    }
    const int b0g = blockIdx.x * 2;
    *(float4*)(fwv + b0g * 2048 + nq * 64 + sub * 4) = *(float4*)a0;
    *(float4*)(fwv + (b0g + 1) * 2048 + nq * 64 + sub * 4) = *(float4*)a1;
  }
}

// ---------------------------------------------------------------------------
// k_attn2: FUSED ih + attn, one block per b. (R15 verbatim)
// ---------------------------------------------------------------------------
__global__ __launch_bounds__(256, 4) void k_attn2(
    const float* __restrict__ fwv, const float* __restrict__ x,
    const unsigned short* __restrict__ Wbf, const float* __restrict__ rs,
    const float* __restrict__ Ab, const float* __restrict__ Kb,
    const float* __restrict__ Wv, const float* __restrict__ Wr,
    const float* __restrict__ kfm, const float* __restrict__ bfm,
    const float* __restrict__ bmf, const float* __restrict__ khi,
    const float* __restrict__ bhi, float* __restrict__ out0)
{
  __shared__ __align__(16) float smem[8832];   // 35328 B
  float* fwS  = smem;               // 32x68 (2176 f)
  float* pS   = smem + 2176;        // 64x36 (2304 f)
  float* bufA = smem + 4480;        // 32x68 (2176 f)
  float* tS   = smem + 6656;        // 32x68 (2176 f); uS; ssqS in phase I
  float* vS   = smem + 4480;        // 32x132 (4224 f) (alias)
  float* redH = smem + 2176;        // 16x132 (alias of pS)
  float* Kf   = smem + 4480;        // 32x33 padded (alias, post-vS)
  float* red1 = smem + 5536;        // 8x68
  // phase-I aliases (all dead before their regions are reused):
  unsigned short* xB   = (unsigned short*)(smem + 2176);  // 2048 f (pS)
  unsigned short* cF2s = (unsigned short*)(smem + 4480);  // 1024 f (bufA)
  float*          ssqS = smem + 6656;                     // 2048 f (tS)

  const int b = blockIdx.x, t = threadIdx.x;
  const int tn = t >> 4, te = t & 15;
  const int n0 = tn * 2, e0 = te * 8, d0 = te * 4;
  const int w = t >> 6, lane = t & 63;

  // ---- stage fwS + xB(bf16 x) + cF2(bf16 c^2) -----------------------------
#pragma unroll
  for (int k = 0; k < 2; k++) {
    int lin = t + 256 * k; int nn = lin >> 4; int c0 = (lin & 15) << 2;
    *(float4*)&fwS[lidx(nn, c0)] = *(const float4*)(fwv + b * 2048 + nn * 64 + c0);
  }
#pragma unroll
  for (int k = 0; k < 4; k++) {
    int ch = t + 256 * k;            // 0..1023 = 64 f x 16 fq
    int f = ch >> 4, fq = ch & 15;
    int dg = fq >> 1, half = fq & 1;
    float4 v = *(const float4*)(x + (b * 64 + f) * 64 + fq * 4);
    unsigned p0 = f2bf(v.x) | ((unsigned)f2bf(v.y) << 16);
    unsigned p1 = f2bf(v.z) | ((unsigned)f2bf(v.w) << 16);
    *(uint2*)&xB[f * 64 + ((dg ^ (f & 7)) << 3) + half * 4] = make_uint2(p0, p1);
  }
#pragma unroll
  for (int k = 0; k < 2; k++) {
    int lin = t + 256 * k;           // 0..511 = 32 n x 16 fq
    int n = lin >> 4, f0 = (lin & 15) << 2;
    float4 v = *(const float4*)(rs + b * 2048 + n * 64 + f0);
    unsigned short t4[4] = {f2bf(v.x * v.x), f2bf(v.y * v.y),
                            f2bf(v.z * v.z), f2bf(v.w * v.w)};
    *(uint2*)&cF2s[n * 64 + f0] = *(uint2*)t4;
  }
  __syncthreads();

  // ---- phase I: ssq via MFMA; wave w handles n in [w*8, w*8+8) ------------
  {
    const int m = lane & 15, q = lane >> 4, ms = m & 7;
    bf16x8 a_[4][2];
#pragma unroll
    for (int mi = 0; mi < 4; mi++) {
      const unsigned short* bp = xB + (mi * 16 + m) * 64;
#pragma unroll
      for (int kk = 0; kk < 2; kk++)
        a_[mi][kk] = *(const bf16x8*)&bp[((kk * 4 + q) ^ ms) << 3];
    }
#pragma unroll 2
    for (int nn = 0; nn < 8; nn++) {
      const int n = w * 8 + nn;
      bf16x8 bf[4][2];
#pragma unroll
      for (int ci = 0; ci < 4; ci++) {
        const unsigned short* bp = Wbf + n * 4096 + (ci * 16 + m) * 64;
#pragma unroll
        for (int kk = 0; kk < 2; kk++)
          bf[ci][kk] = *(const bf16x8*)&bp[((kk * 4 + q) ^ ms) << 3];
      }
      float ps[4] = {0.f, 0.f, 0.f, 0.f};
      const unsigned short* cf = cF2s + n * 64 + q * 4;
#pragma unroll
      for (int mi = 0; mi < 4; mi++) {
        float cfv[4];
#pragma unroll
        for (int r = 0; r < 4; r++)
          cfv[r] = __uint_as_float((unsigned)cf[mi * 16 + r] << 16);
#pragma unroll
        for (int ci = 0; ci < 4; ci++) {
          floatx4 c0 = {0.f, 0.f, 0.f, 0.f};
          c0 = __builtin_amdgcn_mfma_f32_16x16x32_bf16(a_[mi][0], bf[ci][0], c0, 0, 0, 0);
          c0 = __builtin_amdgcn_mfma_f32_16x16x32_bf16(a_[mi][1], bf[ci][1], c0, 0, 0, 0);
#pragma unroll
          for (int r = 0; r < 4; r++) { float tv = c0[r]; ps[ci] += cfv[r] * tv * tv; }
        }
      }
#pragma unroll
      for (int ci = 0; ci < 4; ci++) {
        ps[ci] += __shfl_xor(ps[ci], 16, 64);
        ps[ci] += __shfl_xor(ps[ci], 32, 64);
      }
      if (q == 0) {
#pragma unroll
        for (int ci = 0; ci < 4; ci++)
          ssqS[n * 64 + ci * 16 + m] = ps[ci];
      }
    }
  }
  __syncthreads();

  // ---- FM partial into a register (same order as old tail) ----------------
  float p_reg = 0.f;
  {
    const int c = t & 63, nqf = t >> 6;
#pragma unroll
    for (int k = 0; k < 8; k++) {
      int nn = nqf * 8 + k;
      float fv = fwS[lidx(nn, c)];
      float sv = ssqS[nn * 64 + c];
      p_reg += (fv * fv - sv) * kfm[nn];
    }
  }
  __syncthreads();

  // ---- phase II: attn body (R13 verbatim) ---------------------------------
  for (int h = 0; h < 2; h++) {
    float tacc[2][4] = {};
    for (int half = 0; half < 2; half++) {
#pragma unroll
      for (int k = 0; k < 2; k++) {
        int lin = t + 256 * k; int d = lin >> 4; int c0 = (lin & 15) << 2;
        *(float4*)&bufA[lidx(d, c0)] =
            *(const float4*)(Ab + h * 4096 + (half * 32 + d) * 64 + c0);
      }
      __syncthreads();
      for (int dq = 0; dq < 32; dq += 4) {
        float fw0[4], fw1[4];
        *(float4*)fw0 = *(const float4*)&fwS[lidx(n0, half * 32 + dq)];
        *(float4*)fw1 = *(const float4*)&fwS[lidx(n0 + 1, half * 32 + dq)];
#pragma unroll
        for (int j = 0; j < 4; j++) {
          float mr[4];
          *(float4*)mr = *(const float4*)&bufA[lidx(dq + j, d0)];
#pragma unroll
          for (int c = 0; c < 4; c++) {
            tacc[0][c] += fw0[j] * mr[c];
            tacc[1][c] += fw1[j] * mr[c];
          }
        }
      }
      __syncthreads();
    }
    *(float4*)&tS[lidx(n0, d0)] = *(float4*)tacc[0];
    *(float4*)&tS[lidx(n0 + 1, d0)] = *(float4*)tacc[1];
    __syncthreads();
    {
      const int m0 = te * 2;
      float s00 = 0.f, s01 = 0.f, s10 = 0.f, s11 = 0.f;
      for (int kk = 0; kk < 16; kk++) {
        float ta0[4], ta1[4], f0[4], f1[4];
        *(float4*)ta0 = *(const float4*)&tS[lidx(n0, kk * 4)];
        *(float4*)ta1 = *(const float4*)&tS[lidx(n0 + 1, kk * 4)];
        *(float4*)f0 = *(const float4*)&fwS[lidx(m0, kk * 4)];
        *(float4*)f1 = *(const float4*)&fwS[lidx(m0 + 1, kk * 4)];
#pragma unroll
        for (int j = 0; j < 4; j++) {
          s00 += ta0[j] * f0[j]; s01 += ta0[j] * f1[j];
          s10 += ta1[j] * f0[j]; s11 += ta1[j] * f1[j];
        }
      }
      pS[(h * 32 + n0) * 36 + m0] = s00;
      pS[(h * 32 + n0) * 36 + m0 + 1] = s01;
      pS[(h * 32 + n0 + 1) * 36 + m0] = s10;
      pS[(h * 32 + n0 + 1) * 36 + m0 + 1] = s11;
    }
    __syncthreads();
  }

  {
    const int r = t >> 2, sub = t & 3;
    const int base = r * 36 + sub * 8;
    float v0[4], v1[4];
    *(float4*)v0 = *(const float4*)&pS[base];
    *(float4*)v1 = *(const float4*)&pS[base + 4];
    float mx = fmaxf(fmaxf(fmaxf(v0[0], v0[1]), fmaxf(v0[2], v0[3])),
                     fmaxf(fmaxf(v1[0], v1[1]), fmaxf(v1[2], v1[3])));
    mx = fmaxf(mx, __shfl_xor(mx, 1, 64));
    mx = fmaxf(mx, __shfl_xor(mx, 2, 64));
    float sum = 0.f;
#pragma unroll
    for (int j = 0; j < 4; j++) { v0[j] = __expf(v0[j] - mx); sum += v0[j]; }
#pragma unroll
    for (int j = 0; j < 4; j++) { v1[j] = __expf(v1[j] - mx); sum += v1[j]; }
    sum += __shfl_xor(sum, 1, 64);
    sum += __shfl_xor(sum, 2, 64);
    const float inv = 1.0f / sum;
#pragma unroll
    for (int j = 0; j < 4; j++) { v0[j] *= inv; v1[j] *= inv; }
    *(float4*)&pS[base] = *(float4*)v0;
    *(float4*)&pS[base + 4] = *(float4*)v1;
  }
  __syncthreads();

  {
    float acc[2][8] = {};
    for (int dq = 0; dq < 64; dq += 4) {
      float fw0[4], fw1[4];
      *(float4*)fw0 = *(const float4*)&fwS[lidx(n0, dq)];
      *(float4*)fw1 = *(const float4*)&fwS[lidx(n0 + 1, dq)];
#pragma unroll
      for (int jj = 0; jj < 4; jj++) {
        float w8[8];
        *(float4*)&w8[0] = *(const float4*)(Wv + (dq + jj) * 128 + e0);
        *(float4*)&w8[4] = *(const float4*)(Wv + (dq + jj) * 128 + e0 + 4);
#pragma unroll
        for (int j = 0; j < 8; j++) {
          acc[0][j] += fw0[jj] * w8[j];
          acc[1][j] += fw1[jj] * w8[j];
        }
      }
    }
    *(float4*)&vS[n0 * 132 + e0] = *(float4*)&acc[0][0];
    *(float4*)&vS[n0 * 132 + e0 + 4] = *(float4*)&acc[0][4];
    *(float4*)&vS[(n0 + 1) * 132 + e0] = *(float4*)&acc[1][0];
    *(float4*)&vS[(n0 + 1) * 132 + e0 + 4] = *(float4*)&acc[1][4];
  }
  __syncthreads();

  {
    const int h2 = te >> 3;
    float pacc[2][8] = {};
    for (int m4 = 0; m4 < 8; m4++) {
      float p0v[4], p1v[4];
      *(float4*)p0v = *(const float4*)&pS[(h2 * 32 + n0) * 36 + m4 * 4];
      *(float4*)p1v = *(const float4*)&pS[(h2 * 32 + n0 + 1) * 36 + m4 * 4];
#pragma unroll
      for (int mm = 0; mm < 4; mm++) {
        const int m = m4 * 4 + mm;
        float vr[8];
        *(float4*)&vr[0] = *(const float4*)&vS[m * 132 + e0];
        *(float4*)&vr[4] = *(const float4*)&vS[m * 132 + e0 + 4];
#pragma unroll
        for (int j = 0; j < 8; j++) {
          pacc[0][j] += p0v[mm] * vr[j];
          pacc[1][j] += p1v[mm] * vr[j];
        }
      }
    }
    for (int dq = 0; dq < 64; dq += 4) {
      float fw0[4], fw1[4];
      *(float4*)fw0 = *(const float4*)&fwS[lidx(n0, dq)];
      *(float4*)fw1 = *(const float4*)&fwS[lidx(n0 + 1, dq)];
#pragma unroll
      for (int jj = 0; jj < 4; jj++) {
        float w8[8];
        *(float4*)&w8[0] = *(const float4*)(Wr + (dq + jj) * 128 + e0);
        *(float4*)&w8[4] = *(const float4*)(Wr + (dq + jj) * 128 + e0 + 4);
#pragma unroll
        for (int j = 0; j < 8; j++) {
          pacc[0][j] += fw0[jj] * w8[j];
          pacc[1][j] += fw1[jj] * w8[j];
        }
      }
    }
    __syncthreads();
    {
      float kh0 = khi[n0], kh1 = khi[n0 + 1];
      float ph[8];
#pragma unroll
      for (int j = 0; j < 8; j++)
        ph[j] = kh0 * fmaxf(pacc[0][j], 0.f) + kh1 * fmaxf(pacc[1][j], 0.f);
      *(float4*)&redH[tn * 132 + e0] = *(float4*)&ph[0];
      *(float4*)&redH[tn * 132 + e0 + 4] = *(float4*)&ph[4];
    }
  }
  // ---- stage Kf with 33-stride pad ----------------------------------------
  {
    const int p4 = t * 4;
    float4 kv = *(const float4*)(Kb + p4);
    const int n = p4 >> 5, r = p4 & 31;
    Kf[n * 33 + r]     = kv.x;
    Kf[n * 33 + r + 1] = kv.y;
    Kf[n * 33 + r + 2] = kv.z;
    Kf[n * 33 + r + 3] = kv.w;
  }
  __syncthreads();

  // ---- MF stage A: u = Kf . fwS  (into uS = tS region, dead) --------------
  {
    float acc[2][4] = {{0, 0, 0, 0}, {0, 0, 0, 0}};
    for (int r = 0; r < 32; r++) {
      const float k0 = Kf[n0 * 33 + r];
      const float k1 = Kf[(n0 + 1) * 33 + r];
      float fr[4];
      *(float4*)fr = *(const float4*)&fwS[lidx(r, d0)];
#pragma unroll
      for (int i = 0; i < 4; i++) {
        acc[0][i] += k0 * fr[i];
        acc[1][i] += k1 * fr[i];
      }
    }
    *(float4*)&tS[lidx(n0, d0)] = *(float4*)acc[0];
    *(float4*)&tS[lidx(n0 + 1, d0)] = *(float4*)acc[1];
  }
  __syncthreads();

  if (t < 128) {
    float s = 0.f;
#pragma unroll
    for (int k = 0; k < 16; k++) s += redH[k * 132 + t];
    out0[b * 256 + 128 + t] = s + bhi[t];
  }
  {
    const int c = t & 63, nq = t >> 6;
    red1[nq * 68 + c] = p_reg;
    // MF stage B: hmf = sum_l fw[l,c] * u[l,c] over this nq's 8 rows
    float hmf = 0.f;
#pragma unroll
    for (int l8 = 0; l8 < 8; l8++) {
      const int l = nq * 8 + l8;
      hmf += fwS[lidx(l, c)] * tS[lidx(l, c)];
    }
    red1[(4 + nq) * 68 + c] = hmf;
  }
  __syncthreads();
  if (t < 64) {
    out0[b * 256 + t] = red1[t] + red1[68 + t] + red1[136 + t] + red1[204 + t] + bfm[t];
    float h2 = red1[272 + t] + red1[340 + t] + red1[408 + t] + red1[476 + t];
    out0[b * 256 + 64 + t] = 0.5f * h2 + bmf[t];
  }
}

// ---------------------------------------------------------------------------
extern "C" void kernel_launch(void* const* d_in, const int* in_sizes, int n_in,
                              void* d_out, int out_size, void* d_ws, size_t ws_size,
                              hipStream_t stream) {
  (void)in_sizes; (void)n_in; (void)out_size; (void)ws_size;
  const float* x     = (const float*)d_in[0];
  const float* W     = (const float*)d_in[1];
  const float* rinit = (const float*)d_in[2];
  const float* kfm   = (const float*)d_in[3];
  const float* bfm   = (const float*)d_in[4];
  const float* kmf   = (const float*)d_in[5];
  const float* bmf   = (const float*)d_in[6];
  const float* khi   = (const float*)d_in[7];
  const float* bhi   = (const float*)d_in[8];
  const float* Wq    = (const float*)d_in[9];
  const float* Wk    = (const float*)d_in[10];
  const float* Wv    = (const float*)d_in[11];
  const float* Wr    = (const float*)d_in[12];

  float* out0 = (float*)d_out;
  float* rs   = out0 + 1024 * 256;  // routing_score [B,32,64,1]

  float* ws   = (float*)d_ws;       // 24 MB
  float* Abuf = ws;                 // [2][64][64] = 8192 f
  float* Kbuf = ws + 8192;          // [32][32]    = 1024 f
  float* Qbuf = ws + 16384;         // [32][64][64] = 131072 f
  unsigned short* Wbf = (unsigned short*)(ws + 262144);  // [32][4096] bf16
  float* fwv  = ws + 2097152;       // [B,32,64]

  k_prep2<<<73, 256, 0, stream>>>(W, Wq, Wk, kmf, Qbuf, Abuf, Kbuf, Wbf);
  k_route3<<<512, 512, 0, stream>>>(x, W, rinit, Qbuf, rs, fwv);
  k_attn2<<<1024, 256, 0, stream>>>(fwv, x, Wbf, rs, Abuf, Kbuf, Wv, Wr,
                                    kfm, bfm, bmf, khi, bhi, out0);
}

// Round 10
// 251.210 us; speedup vs baseline: 1.0531x; 1.0200x over previous
//
#include <hip/hip_runtime.h>

// CapsuleLayer fused pipeline, round 17 — CONSOLIDATION.
//  - R16 POST-MORTEM: no-max softmax = -1.5us (matches CORRECTED model:
//    softmax is only ~0.7us/iter of LDS time; R14's 84-op count was wrong).
//    Fusion (attn2) vs split: non-route 150.7/158.8 (fused, 2 runs) vs 153.7
//    (split) -> wash within +/-5us noise. Hold best-measured total: R13 split
//    (252.2us).
//  - R17 = R13 structure verbatim + no-max softmax (verified isolated win,
//    absmax 0.125 passes per R11/R14/R16).
//  - Route model status: ~97us = LDS-issue (~50) + L2 Q/W streams (~29) +
//    barriers (~18). Remaining levers are VGPR-infeasible (xs reg-cache ->
//    128-VGPR occupancy cliff), measured regressions (tile/block variants
//    R11/R14), or precision gambles (bf16 Q: ~15us, absmax risk). If this
//    round lands >=252, structure is at its plateau.
//  - NO cooperative launches (R6 lesson: harness graph capture fails).

#define EPS_SQ 1e-7f

typedef __attribute__((ext_vector_type(8))) short bf16x8;
typedef __attribute__((ext_vector_type(4))) float floatx4;

__device__ __forceinline__ int lidx(int r, int c) {
  // 64-col fp32 tile, row stride 68 dwords, quad-swizzle (legacy kernels)
  return r * 68 + ((((c >> 2) ^ (r >> 2)) & 15) << 2) + (c & 3);
}
__device__ __forceinline__ int lidx64(int r, int c) {
  // unpadded 64-col fp32 tile, XOR swizzle at float4 granularity.
  // R10: include r>>2 so rows stepping by 4 rotate bank-quads.
  return r * 64 + ((((c >> 2) ^ r ^ (r >> 2)) & 15) << 2) + (c & 3);
}
__device__ __forceinline__ unsigned short f2bf(float f) {
  unsigned u = __float_as_uint(f);
  u += 0x7FFFu + ((u >> 16) & 1u);   // RNE
  return (unsigned short)(u >> 16);
}

// ---------------------------------------------------------------------------
// k_prep2: bid<32: Q_n = M_n.M_n^T ; bid 32..39: A_h = Wq_h.Wk_h^T ;
//          bid 40: symmetric pair matrix K from kmf ;
//          bid 41..72: Wbf = W in bf16 MFMA-B-fragment layout.
// ---------------------------------------------------------------------------
__global__ __launch_bounds__(256) void k_prep2(
    const float* __restrict__ W, const float* __restrict__ Wq,
    const float* __restrict__ Wk, const float* __restrict__ kmf,
    float* __restrict__ Qb, float* __restrict__ Ab, float* __restrict__ Kb,
    unsigned short* __restrict__ Wbf)
{
  const int t = threadIdx.x;
  if (blockIdx.x < 32) {
    __shared__ __align__(16) float Mn[64 * 68];
    const int n = blockIdx.x;
#pragma unroll
    for (int k = 0; k < 4; k++) {
      int lin = t + 256 * k; int d = lin >> 4; int c0 = (lin & 15) << 2;
      *(float4*)&Mn[lidx(d, c0)] = *(const float4*)(W + d * 2048 + n * 64 + c0);
    }
    __syncthreads();
    const int d1 = (t >> 4) * 4, d2 = (t & 15) * 4;
    float acc[4][4] = {};
    for (int cq = 0; cq < 64; cq += 4) {
      float m1[4][4], m2[4][4];
#pragma unroll
      for (int i = 0; i < 4; i++) *(float4*)m1[i] = *(const float4*)&Mn[lidx(d1 + i, cq)];
#pragma unroll
      for (int j = 0; j < 4; j++) *(float4*)m2[j] = *(const float4*)&Mn[lidx(d2 + j, cq)];
#pragma unroll
      for (int i = 0; i < 4; i++)
#pragma unroll
        for (int j = 0; j < 4; j++) {
          float s = 0.f;
#pragma unroll
          for (int k = 0; k < 4; k++) s += m1[i][k] * m2[j][k];
          acc[i][j] += s;
        }
    }
#pragma unroll
    for (int i = 0; i < 4; i++)
      *(float4*)(Qb + n * 4096 + (d1 + i) * 64 + d2) = *(float4*)acc[i];
  } else if (blockIdx.x < 40) {
    __shared__ __align__(16) float wkS[64 * 68];
    __shared__ __align__(16) float wqS[16 * 68];
    const int hb = blockIdx.x - 32;
    const int h = hb & 1, rg = hb >> 1;
#pragma unroll
    for (int k = 0; k < 4; k++) {
      int lin = t + 256 * k; int dp = lin >> 4; int e0 = (lin & 15) << 2;
      *(float4*)&wkS[lidx(dp, e0)] = *(const float4*)(Wk + dp * 128 + h * 64 + e0);
    }
    {
      int dl = t >> 4, e0 = (t & 15) << 2;
      *(float4*)&wqS[lidx(dl, e0)] = *(const float4*)(Wq + (rg * 16 + dl) * 128 + h * 64 + e0);
    }
    __syncthreads();
    const int dl = t >> 4, dp0 = (t & 15) << 2;
    float acc[4] = {};
    for (int e = 0; e < 64; e += 4) {
      float q4[4];
      *(float4*)q4 = *(const float4*)&wqS[lidx(dl, e)];
#pragma unroll
      for (int c = 0; c < 4; c++) {
        float mr[4];
        *(float4*)mr = *(const float4*)&wkS[lidx(dp0 + c, e)];
        acc[c] += q4[0] * mr[0] + q4[1] * mr[1] + q4[2] * mr[2] + q4[3] * mr[3];
      }
    }
    *(float4*)(Ab + h * 4096 + (rg * 16 + dl) * 64 + dp0) = *(float4*)acc;
  } else if (blockIdx.x == 40) {
    __shared__ float Ks[1024];
    *(float4*)&Ks[t * 4] = make_float4(0.f, 0.f, 0.f, 0.f);
    __syncthreads();
    if (t < 248) {
#pragma unroll
      for (int j = 0; j < 2; j++) {
        int p = t * 2 + j;
        if (p < 496) {
          int l = 0, rem = p;
          while (rem >= 31 - l) { rem -= 31 - l; ++l; }
          int r = l + 1 + rem;
          float v = kmf[p];
          Ks[l * 32 + r] = v;
          Ks[r * 32 + l] = v;
        }
      }
    }
    __syncthreads();
    *(float4*)&Kb[t * 4] = *(const float4*)&Ks[t * 4];
  } else {
    // Wbf: per n, element (c,d) at Wbf[n*4096 + c*64 + ((dg^(c&7))<<3) + dl],
    // dg=d>>3, dl=d&7 -- the exact wB layout k_ih used to build per-block.
    const int n = blockIdx.x - 41;
#pragma unroll
    for (int k = 0; k < 2; k++) {
      int lin = t + 256 * k;          // 0..511 = 64 c x 8 dg
      int c = lin >> 3, dg = lin & 7;
      unsigned short tmp[8];
#pragma unroll
      for (int dl = 0; dl < 8; dl++)
        tmp[dl] = f2bf(W[(dg * 8 + dl) * 2048 + n * 64 + c]);
      *(uint4*)&Wbf[n * 4096 + c * 64 + ((dg ^ (c & 7)) << 3)] = *(uint4*)tmp;
    }
  }
}

// ---------------------------------------------------------------------------
// k_route3: routing for TWO b's per 512-thread block. (R13 + no-max softmax)
// ---------------------------------------------------------------------------
__global__ __launch_bounds__(512, 4) void k_route3(
    const float* __restrict__ x, const float* __restrict__ W,
    const float* __restrict__ rinit, const float* __restrict__ Qb,
    float* __restrict__ rs, float* __restrict__ fwv)
{
  __shared__ __align__(16) float smem[2 * 10240];   // 81920 B exactly

  const int t = threadIdx.x;
  const int tb = t >> 8, tt = t & 255;
  const int b = blockIdx.x * 2 + tb;

  float* xs  = smem + tb * 10240;          // 64x64 (swizzled)
  float* bS  = smem + tb * 10240 + 4096;   // 32x64 logits (persistent)
  float* cOw = smem + tb * 10240 + 6144;   // 32x64 cS aliased with owS
  float* xcS = smem + tb * 10240 + 8192;   // 32x64

  // cross-b views for ow / fwv phases
  float* xc0 = smem + 8192;
  float* xc1 = smem + 10240 + 8192;
  float* ow0 = smem + 6144;
  float* ow1 = smem + 10240 + 6144;

  // ---- stage x[b] and rinit ----------------------------------------------
#pragma unroll
  for (int k = 0; k < 4; k++) {
    int lin = tt + 256 * k; int f = lin >> 4; int d0 = (lin & 15) << 2;
    *(float4*)&xs[lidx64(f, d0)] = *(const float4*)(x + b * 4096 + f * 64 + d0);
  }
#pragma unroll
  for (int k = 0; k < 2; k++) {
    int lin = tt + 256 * k; int n = lin >> 4; int f0 = (lin & 15) << 2;
    *(float4*)&bS[lidx64(n, f0)] = *(const float4*)(rinit + n * 64 + f0);
  }
  __syncthreads();

  const int tn = tt >> 4, tlo = tt & 15;
  const int nq = t >> 4, sub = t & 15;     // cross-b mapping: 32 n x 4 cols

  for (int it = 0; it < 4; it++) {
    // ---- cS = softmax over n per f column (per-b), NO max-subtract --------
    // shift-invariant exact math; |logit| <= ~30 -> exp <= 1e13, fp32-safe.
    {
      const int nl = tt & 31, fg = tt >> 5;   // fg 0..7
#pragma unroll
      for (int qq = 0; qq < 2; qq++) {
        const int f0 = (fg * 2 + qq) * 4;
        float v[4];
        *(float4*)v = *(const float4*)&bS[lidx64(nl, f0)];
        float e[4];
#pragma unroll
        for (int j = 0; j < 4; j++) {
          e[j] = __expf(v[j]);
          float s = e[j];
          s += __shfl_xor(s, 16, 64);
          s += __shfl_xor(s, 8, 64);
          s += __shfl_xor(s, 4, 64);
          s += __shfl_xor(s, 2, 64);
          s += __shfl_xor(s, 1, 64);
          e[j] /= s;
        }
        *(float4*)&cOw[lidx64(nl, f0)] = *(float4*)e;
      }
    }
    __syncthreads();
    if (it == 3) {
#pragma unroll
      for (int k = 0; k < 2; k++) {
        int lin = tt + 256 * k;              // 0..511
        int n = lin >> 4, fq = lin & 15;
        float4 v = *(const float4*)&cOw[lidx64(n, fq * 4)];
        *(float4*)(rs + b * 2048 + n * 64 + fq * 4) = v;
      }
    }
    // ---- xcS = cS . xs (per-b) -------------------------------------------
    {
      const int n0 = tn * 2, d0 = tlo * 4;
      float acc[2][4] = {{0, 0, 0, 0}, {0, 0, 0, 0}};
      for (int fq = 0; fq < 16; fq++) {
        float c0[4], c1[4];
        *(float4*)c0 = *(const float4*)&cOw[lidx64(n0, fq * 4)];
        *(float4*)c1 = *(const float4*)&cOw[lidx64(n0 + 1, fq * 4)];
#pragma unroll
        for (int j = 0; j < 4; j++) {
          float xr[4];
          *(float4*)xr = *(const float4*)&xs[lidx64(fq * 4 + j, d0)];
#pragma unroll
          for (int i = 0; i < 4; i++) {
            acc[0][i] += c0[j] * xr[i];
            acc[1][i] += c1[j] * xr[i];
          }
        }
      }
      *(float4*)&xcS[lidx64(n0, d0)] = *(float4*)acc[0];
      *(float4*)&xcS[lidx64(n0 + 1, d0)] = *(float4*)acc[1];
    }
    __syncthreads();
    if (it == 3) break;

    // ---- ow = scale * (xc . Q_n): CROSS-B, Q streamed once ----------------
    {
      const float* Qn = Qb + nq * 4096 + sub * 4;
      float y0[4] = {}, y1[4] = {};
#pragma unroll 4
      for (int dq = 0; dq < 16; dq++) {
        float xv0[4], xv1[4];
        *(float4*)xv0 = *(const float4*)&xc0[lidx64(nq, dq * 4)];
        *(float4*)xv1 = *(const float4*)&xc1[lidx64(nq, dq * 4)];
#pragma unroll
        for (int j = 0; j < 4; j++) {
          float4 q = *(const float4*)(Qn + (dq * 4 + j) * 64);
          y0[0] += xv0[j] * q.x; y0[1] += xv0[j] * q.y;
          y0[2] += xv0[j] * q.z; y0[3] += xv0[j] * q.w;
          y1[0] += xv1[j] * q.x; y1[1] += xv1[j] * q.y;
          y1[2] += xv1[j] * q.z; y1[3] += xv1[j] * q.w;
        }
      }
      float xa0[4], xa1[4];
      *(float4*)xa0 = *(const float4*)&xc0[lidx64(nq, sub * 4)];
      *(float4*)xa1 = *(const float4*)&xc1[lidx64(nq, sub * 4)];
      float ps0 = y0[0] * xa0[0] + y0[1] * xa0[1] + y0[2] * xa0[2] + y0[3] * xa0[3];
      float ps1 = y1[0] * xa1[0] + y1[1] * xa1[1] + y1[2] * xa1[2] + y1[3] * xa1[3];
      ps0 += __shfl_xor(ps0, 1, 64); ps0 += __shfl_xor(ps0, 2, 64);
      ps0 += __shfl_xor(ps0, 4, 64); ps0 += __shfl_xor(ps0, 8, 64);
      ps1 += __shfl_xor(ps1, 1, 64); ps1 += __shfl_xor(ps1, 2, 64);
      ps1 += __shfl_xor(ps1, 4, 64); ps1 += __shfl_xor(ps1, 8, 64);
      const float ss0 = ps0 + EPS_SQ, ss1 = ps1 + EPS_SQ;
      const float sc0 = sqrtf(ss0) / (0.5f + ss0);
      const float sc1 = sqrtf(ss1) / (0.5f + ss1);
      float o0[4] = {y0[0] * sc0, y0[1] * sc0, y0[2] * sc0, y0[3] * sc0};
      float o1[4] = {y1[0] * sc1, y1[1] * sc1, y1[2] * sc1, y1[3] * sc1};
      *(float4*)&ow0[lidx64(nq, sub * 4)] = *(float4*)o0;
      *(float4*)&ow1[lidx64(nq, sub * 4)] = *(float4*)o1;
    }
    __syncthreads();

    // ---- bS += xs . owS^T (per-b) ----------------------------------------
    {
      const int n0 = tn * 2, f0 = tlo * 4;
      float acc[2][4] = {{0, 0, 0, 0}, {0, 0, 0, 0}};
      for (int dq = 0; dq < 64; dq += 4) {
        float o[2][4];
        *(float4*)o[0] = *(const float4*)&cOw[lidx64(n0, dq)];
        *(float4*)o[1] = *(const float4*)&cOw[lidx64(n0 + 1, dq)];
#pragma unroll
        for (int i = 0; i < 4; i++) {
          float xr[4];
          *(float4*)xr = *(const float4*)&xs[lidx64(f0 + i, dq)];
#pragma unroll
          for (int k = 0; k < 4; k++) {
            acc[0][i] += o[0][k] * xr[k];
            acc[1][i] += o[1][k] * xr[k];
          }
        }
      }
#pragma unroll
      for (int j = 0; j < 2; j++) {
        float tmp[4];
        *(float4*)tmp = *(const float4*)&bS[lidx64(n0 + j, f0)];
#pragma unroll
        for (int i = 0; i < 4; i++) tmp[i] += acc[j][i];
        *(float4*)&bS[lidx64(n0 + j, f0)] = *(float4*)tmp;
      }
    }
    __syncthreads();
  }

  // ---- fwv = xcS . W: CROSS-B, W streamed once ----------------------------
  {
    const float* Wn = W + nq * 64 + sub * 4;
    float a0[4] = {}, a1[4] = {};
#pragma unroll 4
    for (int dq = 0; dq < 16; dq++) {
      float xv0[4], xv1[4];
      *(float4*)xv0 = *(const float4*)&xc0[lidx64(nq, dq * 4)];
      *(float4*)xv1 = *(const float4*)&xc1[lidx64(nq, dq * 4)];
#pragma unroll
      for (int j = 0; j < 4; j++) {
        float4 w = *(const float4*)(Wn + (dq * 4 + j) * 2048);
        a0[0] += xv0[j] * w.x; a0[1] += xv0[j] * w.y;
        a0[2] += xv0[j] * w.z; a0[3] += xv0[j] * w.w;
        a1[0] += xv1[j] * w.x; a1[1] += xv1[j] * w.y;
        a1[2] += xv1[j] * w.z; a1[3] += xv1[j] * w.w;
      }
    }
    const int b0g = blockIdx.x * 2;
    *(float4*)(fwv + b0g * 2048 + nq * 64 + sub * 4) = *(float4*)a0;
    *(float4*)(fwv + (b0g + 1) * 2048 + nq * 64 + sub * 4) = *(float4*)a1;
  }
}

// ---------------------------------------------------------------------------
// k_ih: ssq via bf16 MFMA. Block = 4 b's x 8 n's, grid 1024. (R12 version)
// ---------------------------------------------------------------------------
__global__ __launch_bounds__(256) void k_ih(
    const float* __restrict__ x, const unsigned short* __restrict__ Wbf,
    const float* __restrict__ rs, float* __restrict__ ssq)
{
  __shared__ __align__(16) unsigned short xB[4 * 64 * 64];   // 32768 B
  __shared__ unsigned short cF2[4 * 8 * 64];                 // 4096 B
  const int n_oct = (blockIdx.x & 3) << 3, b0 = (blockIdx.x >> 2) * 4;
  const int t = threadIdx.x, w = t >> 6, lane = t & 63;

#pragma unroll
  for (int k = 0; k < 16; k++) {
    int ch = t + 256 * k;
    int bb = ch >> 10, rem = ch & 1023;
    int f = rem >> 4, fq = rem & 15;
    int dg = fq >> 1, half = fq & 1;
    float4 v = *(const float4*)(x + ((b0 + bb) * 64 + f) * 64 + fq * 4);
    unsigned p0 = f2bf(v.x) | ((unsigned)f2bf(v.y) << 16);
    unsigned p1 = f2bf(v.z) | ((unsigned)f2bf(v.w) << 16);
    *(uint2*)&xB[bb * 4096 + f * 64 + ((dg ^ (f & 7)) << 3) + half * 4] =
        make_uint2(p0, p1);
  }
#pragma unroll
  for (int nn = 0; nn < 8; nn++) {
    float v = rs[(b0 + w) * 2048 + (n_oct + nn) * 64 + lane];
    cF2[(w * 8 + nn) * 64 + lane] = f2bf(v * v);
  }
  __syncthreads();

  const int m = lane & 15, q = lane >> 4, ms = m & 7;
  bf16x8 a[4][2];
#pragma unroll
  for (int mi = 0; mi < 4; mi++) {
    const unsigned short* bp = xB + w * 4096 + (mi * 16 + m) * 64;
#pragma unroll
    for (int kk = 0; kk < 2; kk++)
      a[mi][kk] = *(const bf16x8*)&bp[((kk * 4 + q) ^ ms) << 3];
  }

  for (int np = 0; np < 4; np++) {
    const int n0 = n_oct + np * 2;
#pragma unroll
    for (int nn = 0; nn < 2; nn++) {
      bf16x8 bf[4][2];
#pragma unroll
      for (int ci = 0; ci < 4; ci++) {
        const unsigned short* bp = Wbf + (n0 + nn) * 4096 + (ci * 16 + m) * 64;
#pragma unroll
        for (int kk = 0; kk < 2; kk++)
          bf[ci][kk] = *(const bf16x8*)&bp[((kk * 4 + q) ^ ms) << 3];
      }
      float ps[4] = {0.f, 0.f, 0.f, 0.f};
      const unsigned short* cf = cF2 + (w * 8 + np * 2 + nn) * 64 + q * 4;
#pragma unroll
      for (int mi = 0; mi < 4; mi++) {
        float cfv[4];
#pragma unroll
        for (int r = 0; r < 4; r++)
          cfv[r] = __uint_as_float((unsigned)cf[mi * 16 + r] << 16);
#pragma unroll
        for (int ci = 0; ci < 4; ci++) {
          floatx4 c0 = {0.f, 0.f, 0.f, 0.f};
          c0 = __builtin_amdgcn_mfma_f32_16x16x32_bf16(a[mi][0], bf[ci][0], c0, 0, 0, 0);
          c0 = __builtin_amdgcn_mfma_f32_16x16x32_bf16(a[mi][1], bf[ci][1], c0, 0, 0, 0);
#pragma unroll
          for (int r = 0; r < 4; r++) { float tv = c0[r]; ps[ci] += cfv[r] * tv * tv; }
        }
      }
#pragma unroll
      for (int ci = 0; ci < 4; ci++) {
        ps[ci] += __shfl_xor(ps[ci], 16, 64);
        ps[ci] += __shfl_xor(ps[ci], 32, 64);
      }
      if (q == 0) {
#pragma unroll
        for (int ci = 0; ci < 4; ci++)
          ssq[(b0 + w) * 2048 + (n0 + nn) * 64 + ci * 16 + m] = ps[ci];
      }
    }
  }
}

// ---------------------------------------------------------------------------
// k_attn: per-b fused attention + FM + MF + high_int. (R13 version)
// ---------------------------------------------------------------------------
__global__ __launch_bounds__(256) void k_attn(
    const float* __restrict__ fwv, const float* __restrict__ ssq,
    const float* __restrict__ Ab, const float* __restrict__ Kb,
    const float* __restrict__ Wv, const float* __restrict__ Wr,
    const float* __restrict__ kfm, const float* __restrict__ bfm,
    const float* __restrict__ bmf, const float* __restrict__ khi,
    const float* __restrict__ bhi, float* __restrict__ out0)
{
  __shared__ __align__(16) float smem[8832];   // 35328 B
  float* fwS  = smem;               // 32x68 (2176 f)
  float* pS   = smem + 2176;        // 64x36 (2304 f)
  float* bufA = smem + 4480;        // 32x68 (2176 f)
  float* tS   = smem + 6656;        // 32x68 (2176 f); later uS (=K.fw)
  float* vS   = smem + 4480;        // 32x132 (4224 f) (alias)
  float* redH = smem + 2176;        // 16x132 (alias of pS)
  float* Kf   = smem + 4480;        // 32x33 padded (alias, post-vS)
  float* red1 = smem + 5536;        // 8x68 (moved +32 for Kf33)

  const int b = blockIdx.x, t = threadIdx.x;
  const int tn = t >> 4, te = t & 15;
  const int n0 = tn * 2, e0 = te * 8, d0 = te * 4;

#pragma unroll
  for (int k = 0; k < 2; k++) {
    int lin = t + 256 * k; int nn = lin >> 4; int c0 = (lin & 15) << 2;
    *(float4*)&fwS[lidx(nn, c0)] = *(const float4*)(fwv + b * 2048 + nn * 64 + c0);
  }
  __syncthreads();

  for (int h = 0; h < 2; h++) {
    float tacc[2][4] = {};
    for (int half = 0; half < 2; half++) {
#pragma unroll
      for (int k = 0; k < 2; k++) {
        int lin = t + 256 * k; int d = lin >> 4; int c0 = (lin & 15) << 2;
        *(float4*)&bufA[lidx(d, c0)] =
            *(const float4*)(Ab + h * 4096 + (half * 32 + d) * 64 + c0);
      }
      __syncthreads();
      for (int dq = 0; dq < 32; dq += 4) {
        float fw0[4], fw1[4];
        *(float4*)fw0 = *(const float4*)&fwS[lidx(n0, half * 32 + dq)];
        *(float4*)fw1 = *(const float4*)&fwS[lidx(n0 + 1, half * 32 + dq)];
#pragma unroll
        for (int j = 0; j < 4; j++) {
          float mr[4];
          *(float4*)mr = *(const float4*)&bufA[lidx(dq + j, d0)];
#pragma unroll
          for (int c = 0; c < 4; c++) {
            tacc[0][c] += fw0[j] * mr[c];
            tacc[1][c] += fw1[j] * mr[c];
          }
        }
      }
      __syncthreads();
    }
    *(float4*)&tS[lidx(n0, d0)] = *(float4*)tacc[0];
    *(float4*)&tS[lidx(n0 + 1, d0)] = *(float4*)tacc[1];
    __syncthreads();
    {
      const int m0 = te * 2;
      float s00 = 0.f, s01 = 0.f, s10 = 0.f, s11 = 0.f;
      for (int kk = 0; kk < 16; kk++) {
        float ta0[4], ta1[4], f0[4], f1[4];
        *(float4*)ta0 = *(const float4*)&tS[lidx(n0, kk * 4)];
        *(float4*)ta1 = *(const float4*)&tS[lidx(n0 + 1, kk * 4)];
        *(float4*)f0 = *(const float4*)&fwS[lidx(m0, kk * 4)];
        *(float4*)f1 = *(const float4*)&fwS[lidx(m0 + 1, kk * 4)];
#pragma unroll
        for (int j = 0; j < 4; j++) {
          s00 += ta0[j] * f0[j]; s01 += ta0[j] * f1[j];
          s10 += ta1[j] * f0[j]; s11 += ta1[j] * f1[j];
        }
      }
      pS[(h * 32 + n0) * 36 + m0] = s00;
      pS[(h * 32 + n0) * 36 + m0 + 1] = s01;
      pS[(h * 32 + n0 + 1) * 36 + m0] = s10;
      pS[(h * 32 + n0 + 1) * 36 + m0 + 1] = s11;
    }
    __syncthreads();
  }

  {
    const int r = t >> 2, sub = t & 3;
    const int base = r * 36 + sub * 8;
    float v0[4], v1[4];
    *(float4*)v0 = *(const float4*)&pS[base];
    *(float4*)v1 = *(const float4*)&pS[base + 4];
    float mx = fmaxf(fmaxf(fmaxf(v0[0], v0[1]), fmaxf(v0[2], v0[3])),
                     fmaxf(fmaxf(v1[0], v1[1]), fmaxf(v1[2], v1[3])));
    mx = fmaxf(mx, __shfl_xor(mx, 1, 64));
    mx = fmaxf(mx, __shfl_xor(mx, 2, 64));
    float sum = 0.f;
#pragma unroll
    for (int j = 0; j < 4; j++) { v0[j] = __expf(v0[j] - mx); sum += v0[j]; }
#pragma unroll
    for (int j = 0; j < 4; j++) { v1[j] = __expf(v1[j] - mx); sum += v1[j]; }
    sum += __shfl_xor(sum, 1, 64);
    sum += __shfl_xor(sum, 2, 64);
    const float inv = 1.0f / sum;
#pragma unroll
    for (int j = 0; j < 4; j++) { v0[j] *= inv; v1[j] *= inv; }
    *(float4*)&pS[base] = *(float4*)v0;
    *(float4*)&pS[base + 4] = *(float4*)v1;
  }
  __syncthreads();

  {
    float acc[2][8] = {};
    for (int dq = 0; dq < 64; dq += 4) {
      float fw0[4], fw1[4];
      *(float4*)fw0 = *(const float4*)&fwS[lidx(n0, dq)];
      *(float4*)fw1 = *(const float4*)&fwS[lidx(n0 + 1, dq)];
#pragma unroll
      for (int jj = 0; jj < 4; jj++) {
        float w8[8];
        *(float4*)&w8[0] = *(const float4*)(Wv + (dq + jj) * 128 + e0);
        *(float4*)&w8[4] = *(const float4*)(Wv + (dq + jj) * 128 + e0 + 4);
#pragma unroll
        for (int j = 0; j < 8; j++) {
          acc[0][j] += fw0[jj] * w8[j];
          acc[1][j] += fw1[jj] * w8[j];
        }
      }
    }
    *(float4*)&vS[n0 * 132 + e0] = *(float4*)&acc[0][0];
    *(float4*)&vS[n0 * 132 + e0 + 4] = *(float4*)&acc[0][4];
    *(float4*)&vS[(n0 + 1) * 132 + e0] = *(float4*)&acc[1][0];
    *(float4*)&vS[(n0 + 1) * 132 + e0 + 4] = *(float4*)&acc[1][4];
  }
  __syncthreads();

  {
    const int h2 = te >> 3;
    float pacc[2][8] = {};
    for (int m4 = 0; m4 < 8; m4++) {
      float p0v[4], p1v[4];
      *(float4*)p0v = *(const float4*)&pS[(h2 * 32 + n0) * 36 + m4 * 4];
      *(float4*)p1v = *(const float4*)&pS[(h2 * 32 + n0 + 1) * 36 + m4 * 4];
#pragma unroll
      for (int mm = 0; mm < 4; mm++) {
        const int m = m4 * 4 + mm;
        float vr[8];
        *(float4*)&vr[0] = *(const float4*)&vS[m * 132 + e0];
        *(float4*)&vr[4] = *(const float4*)&vS[m * 132 + e0 + 4];
#pragma unroll
        for (int j = 0; j < 8; j++) {
          pacc[0][j] += p0v[mm] * vr[j];
          pacc[1][j] += p1v[mm] * vr[j];
        }
      }
    }
    for (int dq = 0; dq < 64; dq += 4) {
      float fw0[4], fw1[4];
      *(float4*)fw0 = *(const float4*)&fwS[lidx(n0, dq)];
      *(float4*)fw1 = *(const float4*)&fwS[lidx(n0 + 1, dq)];
#pragma unroll
      for (int jj = 0; jj < 4; jj++) {
        float w8[8];
        *(float4*)&w8[0] = *(const float4*)(Wr + (dq + jj) * 128 + e0);
        *(float4*)&w8[4] = *(const float4*)(Wr + (dq + jj) * 128 + e0 + 4);
#pragma unroll
        for (int j = 0; j < 8; j++) {
          pacc[0][j] += fw0[jj] * w8[j];
          pacc[1][j] += fw1[jj] * w8[j];
        }
      }
    }
    __syncthreads();
    {
      float kh0 = khi[n0], kh1 = khi[n0 + 1];
      float ph[8];
#pragma unroll
      for (int j = 0; j < 8; j++)
        ph[j] = kh0 * fmaxf(pacc[0][j], 0.f) + kh1 * fmaxf(pacc[1][j], 0.f);
      *(float4*)&redH[tn * 132 + e0] = *(float4*)&ph[0];
      *(float4*)&redH[tn * 132 + e0 + 4] = *(float4*)&ph[4];
    }
  }
  // ---- stage Kf with 33-stride pad (banks rotate per row) -----------------
  {
    const int p4 = t * 4;
    float4 kv = *(const float4*)(Kb + p4);
    const int n = p4 >> 5, r = p4 & 31;
    Kf[n * 33 + r]     = kv.x;
    Kf[n * 33 + r + 1] = kv.y;
    Kf[n * 33 + r + 2] = kv.z;
    Kf[n * 33 + r + 3] = kv.w;
  }
  __syncthreads();

  // ---- MF stage A: u = Kf . fwS  (into uS = tS region, dead) --------------
  {
    float acc[2][4] = {{0, 0, 0, 0}, {0, 0, 0, 0}};
    for (int r = 0; r < 32; r++) {
      const float k0 = Kf[n0 * 33 + r];
      const float k1 = Kf[(n0 + 1) * 33 + r];
      float fr[4];
      *(float4*)fr = *(const float4*)&fwS[lidx(r, d0)];
#pragma unroll
      for (int i = 0; i < 4; i++) {
        acc[0][i] += k0 * fr[i];
        acc[1][i] += k1 * fr[i];
      }
    }
    *(float4*)&tS[lidx(n0, d0)] = *(float4*)acc[0];
    *(float4*)&tS[lidx(n0 + 1, d0)] = *(float4*)acc[1];
  }
  __syncthreads();

  if (t < 128) {
    float s = 0.f;
#pragma unroll
    for (int k = 0; k < 16; k++) s += redH[k * 132 + t];
    out0[b * 256 + 128 + t] = s + bhi[t];
  }
  {
    const int c = t & 63, nq = t >> 6;
    float p = 0.f;
#pragma unroll
    for (int k = 0; k < 8; k++) {
      int nn = nq * 8 + k;
      float fv = fwS[lidx(nn, c)];
      float sv = ssq[b * 2048 + nn * 64 + c];
      p += (fv * fv - sv) * kfm[nn];
    }
    red1[nq * 68 + c] = p;
    // MF stage B: hmf = sum_l fw[l,c] * u[l,c] over this nq's 8 rows
    float hmf = 0.f;
#pragma unroll
    for (int l8 = 0; l8 < 8; l8++) {
      const int l = nq * 8 + l8;
      hmf += fwS[lidx(l, c)] * tS[lidx(l, c)];
    }
    red1[(4 + nq) * 68 + c] = hmf;
  }
  __syncthreads();
  if (t < 64) {
    out0[b * 256 + t] = red1[t] + red1[68 + t] + red1[136 + t] + red1[204 + t] + bfm[t];
    float h2 = red1[272 + t] + red1[340 + t] + red1[408 + t] + red1[476 + t];
    out0[b * 256 + 64 + t] = 0.5f * h2 + bmf[t];
  }
}

// ---------------------------------------------------------------------------
extern "C" void kernel_launch(void* const* d_in, const int* in_sizes, int n_in,
                              void* d_out, int out_size, void* d_ws, size_t ws_size,
                              hipStream_t stream) {
  (void)in_sizes; (void)n_in; (void)out_size; (void)ws_size;
  const float* x     = (const float*)d_in[0];
  const float* W     = (const float*)d_in[1];
  const float* rinit = (const float*)d_in[2];
  const float* kfm   = (const float*)d_in[3];
  const float* bfm   = (const float*)d_in[4];
  const float* kmf   = (const float*)d_in[5];
  const float* bmf   = (const float*)d_in[6];
  const float* khi   = (const float*)d_in[7];
  const float* bhi   = (const float*)d_in[8];
  const float* Wq    = (const float*)d_in[9];
  const float* Wk    = (const float*)d_in[10];
  const float* Wv    = (const float*)d_in[11];
  const float* Wr    = (const float*)d_in[12];

  float* out0 = (float*)d_out;
  float* rs   = out0 + 1024 * 256;  // routing_score [B,32,64,1]

  float* ws   = (float*)d_ws;       // 24 MB
  float* Abuf = ws;                 // [2][64][64] = 8192 f
  float* Kbuf = ws + 8192;          // [32][32]    = 1024 f
  float* Qbuf = ws + 16384;         // [32][64][64] = 131072 f
  unsigned short* Wbf = (unsigned short*)(ws + 262144);  // [32][4096] bf16
  float* fwv  = ws + 2097152;       // [B,32,64]
  float* ssq  = ws + 2 * 2097152;   // [B,32,64]

  k_prep2<<<73, 256, 0, stream>>>(W, Wq, Wk, kmf, Qbuf, Abuf, Kbuf, Wbf);
  k_route3<<<512, 512, 0, stream>>>(x, W, rinit, Qbuf, rs, fwv);
  k_ih<<<1024, 256, 0, stream>>>(x, Wbf, rs, ssq);
  k_attn<<<1024, 256, 0, stream>>>(fwv, ssq, Abuf, Kbuf, Wv, Wr,
                                   kfm, bfm, bmf, khi, bhi, out0);
}